// Round 4
// baseline (1489.191 us; speedup 1.0000x reference)
//
#include <hip/hip_runtime.h>
#include <math.h>

#define NUM_USERS 100000
#define NUM_ITEMS 50000
#define N_NODES   150000   // NUM_USERS + NUM_ITEMS
#define LATENT    64
#define N_EDGES   2400000
#define BATCH     16384
#define SCAN_BLK  1024
#define SCAN_GRID ((N_NODES + SCAN_BLK - 1) / SCAN_BLK)   // 147

// Bucketed CSR build: 512 rows per bucket
#define BKT_ROWS  512
#define BKT_SHIFT 9
#define NUM_BKT   ((N_NODES + BKT_ROWS - 1) / BKT_ROWS)   // 293

// bf16 helpers (values are small/finite; RNE)
__device__ __forceinline__ unsigned short f2bf(float f) {
    unsigned u = __float_as_uint(f);
    u = (u + 0x7FFF + ((u >> 16) & 1)) >> 16;
    return (unsigned short)u;
}
__device__ __forceinline__ float bf2f(unsigned short h) {
    return __uint_as_float(((unsigned)h) << 16);
}

// ---------------------------------------------------------------------------
// table = bf16(concat(user_emb, item_emb))
// ---------------------------------------------------------------------------
__global__ void k_concat_bf16(const float4* __restrict__ ue,
                              const float4* __restrict__ ie,
                              ushort4* __restrict__ cur) {
    int i = blockIdx.x * blockDim.x + threadIdx.x;
    const int nU4 = NUM_USERS * (LATENT / 4);
    const int nT4 = N_NODES   * (LATENT / 4);
    if (i >= nT4) return;
    float4 v = (i < nU4) ? ue[i] : ie[i - nU4];
    ushort4 o;
    o.x = f2bf(v.x); o.y = f2bf(v.y); o.z = f2bf(v.z); o.w = f2bf(v.w);
    cur[i] = o;
}

// ---------------------------------------------------------------------------
// vsel[b, 0:64] = user_emb[users[b]] ; vsel[b,64:128] = item_emb[items[b]]
// ---------------------------------------------------------------------------
__global__ void k_sel_init(const int* __restrict__ users,
                           const int* __restrict__ items,
                           const float* __restrict__ ue,
                           const float* __restrict__ ie,
                           float* __restrict__ vsel) {
    int t = blockIdx.x * blockDim.x + threadIdx.x;
    int b = t >> 6, d = t & 63;
    vsel[b * 128 + d]      = ue[users[b] * 64 + d];
    vsel[b * 128 + 64 + d] = ie[items[b] * 64 + d];
}

// ---------------------------------------------------------------------------
// CSR build step 1: histogram of row degrees
// ---------------------------------------------------------------------------
__global__ void k_hist(const int* __restrict__ rows, int* __restrict__ counts) {
    int e = blockIdx.x * blockDim.x + threadIdx.x;
    if (e < N_EDGES) atomicAdd(&counts[rows[e]], 1);
}

// ---------------------------------------------------------------------------
// CSR build step 2: exclusive scan (3-phase)
// ---------------------------------------------------------------------------
__global__ __launch_bounds__(SCAN_BLK) void k_scan_a(const int* __restrict__ counts,
                                                     int* __restrict__ startArr,
                                                     int* __restrict__ bsum) {
    __shared__ int sh[SCAN_BLK];
    int i = blockIdx.x * SCAN_BLK + threadIdx.x;
    int v = (i < N_NODES) ? counts[i] : 0;
    sh[threadIdx.x] = v;
    __syncthreads();
    for (int off = 1; off < SCAN_BLK; off <<= 1) {
        int t = (threadIdx.x >= off) ? sh[threadIdx.x - off] : 0;
        __syncthreads();
        sh[threadIdx.x] += t;
        __syncthreads();
    }
    if (i < N_NODES) startArr[i] = sh[threadIdx.x] - v;           // exclusive
    if (threadIdx.x == SCAN_BLK - 1) bsum[blockIdx.x] = sh[threadIdx.x];
}

__global__ __launch_bounds__(256) void k_scan_b(int* __restrict__ bsum, int n) {
    __shared__ int sh[256];
    int v = (threadIdx.x < n) ? bsum[threadIdx.x] : 0;
    sh[threadIdx.x] = v;
    __syncthreads();
    for (int off = 1; off < 256; off <<= 1) {
        int t = (threadIdx.x >= off) ? sh[threadIdx.x - off] : 0;
        __syncthreads();
        sh[threadIdx.x] += t;
        __syncthreads();
    }
    if (threadIdx.x < n) bsum[threadIdx.x] = sh[threadIdx.x] - v; // exclusive
}

__global__ __launch_bounds__(SCAN_BLK) void k_scan_c(int* __restrict__ startArr,
                                                     const int* __restrict__ bsum) {
    int i = blockIdx.x * SCAN_BLK + threadIdx.x;
    if (i < N_NODES) startArr[i] += bsum[blockIdx.x];
}

// ---------------------------------------------------------------------------
// Fill pass 1: scatter edges into per-bucket staging regions (atomic append).
// Record packed to 8B: x = rowLo(9b) | col<<9 (18b), y = fp32 val bits.
// Staging shares the final CSR layout's bucket windows (same counts).
// ---------------------------------------------------------------------------
__global__ void k_fill_bucket(const int* __restrict__ rows,
                              const int* __restrict__ cols,
                              const float* __restrict__ vals,
                              const int* __restrict__ startArr,
                              int* __restrict__ bcnt,
                              int2* __restrict__ staged) {
    int e = blockIdx.x * blockDim.x + threadIdx.x;
    if (e >= N_EDGES) return;
    int r = rows[e];
    int b = r >> BKT_SHIFT;
    int base = startArr[b << BKT_SHIFT];
    int pos  = base + atomicAdd(&bcnt[b], 1);
    staged[pos] = make_int2((r & (BKT_ROWS - 1)) | (cols[e] << BKT_SHIFT),
                            __float_as_int(vals[e]));
}

// ---------------------------------------------------------------------------
// Fill pass 2: one workgroup per bucket. Row-local offsets via LDS counters;
// all writes land in the bucket's contiguous ~64KB window (single XCD) so
// cachelines become fully dirty before writeback.
// ---------------------------------------------------------------------------
__global__ __launch_bounds__(256) void k_fill_final(const int* __restrict__ startArr,
                                                    const int2* __restrict__ staged,
                                                    int2* __restrict__ edges) {
    __shared__ int sStart[BKT_ROWS];
    __shared__ int sCnt[BKT_ROWS];
    int b = blockIdx.x;
    int rowBase = b << BKT_SHIFT;
    int numRows = min(BKT_ROWS, N_NODES - rowBase);
    int base = startArr[rowBase];
    int end  = (b == NUM_BKT - 1) ? N_EDGES : startArr[rowBase + BKT_ROWS];
    for (int i = threadIdx.x; i < numRows; i += 256) {
        sStart[i] = startArr[rowBase + i] - base;
        sCnt[i]   = 0;
    }
    __syncthreads();
    int count = end - base;
    for (int t = threadIdx.x; t < count; t += 256) {
        int2 rec = staged[base + t];
        int rl = rec.x & (BKT_ROWS - 1);
        int c  = ((unsigned)rec.x) >> BKT_SHIFT;
        int off = sStart[rl] + atomicAdd(&sCnt[rl], 1);
        edges[base + off] = make_int2(c, rec.y);
    }
}

// ---------------------------------------------------------------------------
// Gather SpMM (bf16 table): one wave per row, lane = latent dim, unroll 4.
// ---------------------------------------------------------------------------
__global__ __launch_bounds__(256) void k_spmm_csr(const int* __restrict__ startArr,
                                                  const int* __restrict__ counts,
                                                  const int2* __restrict__ edges,
                                                  const unsigned short* __restrict__ cur,
                                                  unsigned short* __restrict__ nxt) {
    int row  = blockIdx.x * 4 + (threadIdx.x >> 6);
    int lane = threadIdx.x & 63;
    if (row >= N_NODES) return;
    row = __builtin_amdgcn_readfirstlane(row);
    int s = __builtin_amdgcn_readfirstlane(startArr[row]);
    int n = __builtin_amdgcn_readfirstlane(counts[row]);
    float acc = 0.f;
    int j = 0;
    for (; j + 4 <= n; j += 4) {
        int2 e0 = edges[s + j + 0];
        int2 e1 = edges[s + j + 1];
        int2 e2 = edges[s + j + 2];
        int2 e3 = edges[s + j + 3];
        float x0 = bf2f(cur[(size_t)e0.x * 64 + lane]);
        float x1 = bf2f(cur[(size_t)e1.x * 64 + lane]);
        float x2 = bf2f(cur[(size_t)e2.x * 64 + lane]);
        float x3 = bf2f(cur[(size_t)e3.x * 64 + lane]);
        acc = fmaf(__int_as_float(e0.y), x0, acc);
        acc = fmaf(__int_as_float(e1.y), x1, acc);
        acc = fmaf(__int_as_float(e2.y), x2, acc);
        acc = fmaf(__int_as_float(e3.y), x3, acc);
    }
    for (; j < n; j++) {
        int2 e = edges[s + j];
        acc = fmaf(__int_as_float(e.y), bf2f(cur[(size_t)e.x * 64 + lane]), acc);
    }
    nxt[(size_t)row * 64 + lane] = f2bf(acc);
}

// ---------------------------------------------------------------------------
// Fused layer-3 + layer-2 gather_add at selected rows.
// ---------------------------------------------------------------------------
__global__ __launch_bounds__(256) void k_spmm_sel(const int* __restrict__ users,
                                                  const int* __restrict__ items,
                                                  const int* __restrict__ startArr,
                                                  const int* __restrict__ counts,
                                                  const int2* __restrict__ edges,
                                                  const unsigned short* __restrict__ cur,
                                                  float* __restrict__ vsel) {
    int wave = blockIdx.x * 4 + (threadIdx.x >> 6);
    int lane = threadIdx.x & 63;
    int b, row;
    float* dst;
    if (wave < BATCH) {
        b = wave; row = users[b];
        dst = &vsel[b * 128 + lane];
    } else {
        b = wave - BATCH; row = NUM_USERS + items[b];
        dst = &vsel[b * 128 + 64 + lane];
    }
    int s = startArr[row];
    int n = counts[row];
    float acc = bf2f(cur[(size_t)row * 64 + lane]);   // layer-2 contribution
    int j = 0;
    for (; j + 4 <= n; j += 4) {
        int2 e0 = edges[s + j + 0];
        int2 e1 = edges[s + j + 1];
        int2 e2 = edges[s + j + 2];
        int2 e3 = edges[s + j + 3];
        float x0 = bf2f(cur[(size_t)e0.x * 64 + lane]);
        float x1 = bf2f(cur[(size_t)e1.x * 64 + lane]);
        float x2 = bf2f(cur[(size_t)e2.x * 64 + lane]);
        float x3 = bf2f(cur[(size_t)e3.x * 64 + lane]);
        acc = fmaf(__int_as_float(e0.y), x0, acc);
        acc = fmaf(__int_as_float(e1.y), x1, acc);
        acc = fmaf(__int_as_float(e2.y), x2, acc);
        acc = fmaf(__int_as_float(e3.y), x3, acc);
    }
    for (; j < n; j++) {
        int2 e = edges[s + j];
        acc = fmaf(__int_as_float(e.y), bf2f(cur[(size_t)e.x * 64 + lane]), acc);
    }
    *dst += acc;
}

// ---------------------------------------------------------------------------
// vsel += bf16 src at selected rows (after layer 1)
// ---------------------------------------------------------------------------
__global__ void k_gather_add(const int* __restrict__ users,
                             const int* __restrict__ items,
                             const unsigned short* __restrict__ src,
                             float* __restrict__ vsel) {
    int t = blockIdx.x * blockDim.x + threadIdx.x;
    int b = t >> 6, d = t & 63;
    vsel[b * 128 + d]      += bf2f(src[(size_t)users[b] * 64 + d]);
    vsel[b * 128 + 64 + d] += bf2f(src[(size_t)(NUM_USERS + items[b]) * 64 + d]);
}

// ---------------------------------------------------------------------------
// MLP head: one wave per batch row, weights in LDS.
// ---------------------------------------------------------------------------
__global__ __launch_bounds__(256) void k_mlp(const float* __restrict__ vsel,
                                             const float* __restrict__ W0,
                                             const float* __restrict__ b0,
                                             const float* __restrict__ W1,
                                             const float* __restrict__ b1,
                                             const float* __restrict__ Wa,
                                             const float* __restrict__ ba,
                                             float* __restrict__ out) {
    __shared__ float sW0[128 * 64];
    __shared__ float sW1[64 * 32];
    __shared__ float sWa[32];
    __shared__ float sb0[64];
    __shared__ float sb1[32];

    for (int i = threadIdx.x; i < 128 * 64; i += 256) sW0[i] = W0[i];
    for (int i = threadIdx.x; i < 64 * 32;  i += 256) sW1[i] = W1[i];
    if (threadIdx.x < 32) sWa[threadIdx.x] = Wa[threadIdx.x];
    if (threadIdx.x < 64) sb0[threadIdx.x] = b0[threadIdx.x];
    if (threadIdx.x >= 64 && threadIdx.x < 96) sb1[threadIdx.x - 64] = b1[threadIdx.x - 64];
    float sba = ba[0];
    __syncthreads();

    int lane   = threadIdx.x & 63;
    int wave   = blockIdx.x * (blockDim.x >> 6) + (threadIdx.x >> 6);
    int nwaves = gridDim.x * (blockDim.x >> 6);

    for (int b = wave; b < BATCH; b += nwaves) {
        float vlo = vsel[b * 128 + lane]      * 0.25f;
        float vhi = vsel[b * 128 + 64 + lane] * 0.25f;

        float h0 = 0.f;
        #pragma unroll
        for (int k = 0; k < 64; k++) {
            float a = __shfl(vlo, k);
            h0 = fmaf(a, sW0[k * 64 + lane], h0);
        }
        #pragma unroll
        for (int k = 0; k < 64; k++) {
            float a = __shfl(vhi, k);
            h0 = fmaf(a, sW0[(64 + k) * 64 + lane], h0);
        }
        h0 = fmaxf(h0 + sb0[lane], 0.f);

        float h1 = 0.f;
        #pragma unroll
        for (int k = 0; k < 64; k++) {
            float a = __shfl(h0, k);
            if (lane < 32) h1 = fmaf(a, sW1[k * 32 + lane], h1);
        }
        float contrib = 0.f;
        if (lane < 32) {
            h1 = fmaxf(h1 + sb1[lane], 0.f);
            contrib = h1 * sWa[lane];
        }
        #pragma unroll
        for (int off = 32; off > 0; off >>= 1)
            contrib += __shfl_down(contrib, off);

        if (lane == 0) {
            float logit = contrib + sba;
            out[b] = 1.0f / (1.0f + expf(-logit));
        }
    }
}

// ---------------------------------------------------------------------------
extern "C" void kernel_launch(void* const* d_in, const int* in_sizes, int n_in,
                              void* d_out, int out_size, void* d_ws, size_t ws_size,
                              hipStream_t stream) {
    const int*   users = (const int*)  d_in[0];
    const int*   items = (const int*)  d_in[1];
    const int*   rows  = (const int*)  d_in[2];
    const int*   cols  = (const int*)  d_in[3];
    const float* vals  = (const float*)d_in[4];
    const float* ue    = (const float*)d_in[5];
    const float* ie    = (const float*)d_in[6];
    const float* W0    = (const float*)d_in[7];
    const float* b0    = (const float*)d_in[8];
    const float* W1    = (const float*)d_in[9];
    const float* b1    = (const float*)d_in[10];
    const float* Wa    = (const float*)d_in[11];
    const float* ba    = (const float*)d_in[12];
    float* out = (float*)d_out;

    const size_t nodeElems = (size_t)N_NODES * LATENT;   // 9.6 M
    char* ws = (char*)d_ws;
    unsigned short* tabA = (unsigned short*)ws;  ws += nodeElems * 2;            // 19.2 MB
    unsigned short* tabB = (unsigned short*)ws;  ws += nodeElems * 2;            // 19.2 MB
    float* vsel = (float*)ws;                    ws += (size_t)BATCH * 128 * 4;  // 8.39 MB
    int2*  edges  = (int2*)ws;                   ws += (size_t)N_EDGES * 8;      // 19.2 MB
    int2*  staged = (int2*)ws;                   ws += (size_t)N_EDGES * 8;      // 19.2 MB
    int* counts   = (int*)ws;                    ws += N_NODES * 4;
    int* startArr = (int*)ws;                    ws += N_NODES * 4;
    int* bcnt     = (int*)ws;                    ws += NUM_BKT * 4;
    int* bsum     = (int*)ws;                    ws += SCAN_GRID * 4;

    const int gGrid = (BATCH * 64) / 256;

    // bf16 table + fp32 layer-0 selection
    k_concat_bf16<<<(N_NODES * (LATENT / 4) + 255) / 256, 256, 0, stream>>>(
        (const float4*)ue, (const float4*)ie, (ushort4*)tabA);
    k_sel_init<<<gGrid, 256, 0, stream>>>(users, items, ue, ie, vsel);

    // ---- CSR build ----
    hipMemsetAsync(counts, 0, N_NODES * 4, stream);
    hipMemsetAsync(bcnt,   0, NUM_BKT * 4, stream);
    k_hist<<<(N_EDGES + 255) / 256, 256, 0, stream>>>(rows, counts);
    k_scan_a<<<SCAN_GRID, SCAN_BLK, 0, stream>>>(counts, startArr, bsum);
    k_scan_b<<<1, 256, 0, stream>>>(bsum, SCAN_GRID);
    k_scan_c<<<SCAN_GRID, SCAN_BLK, 0, stream>>>(startArr, bsum);
    k_fill_bucket<<<(N_EDGES + 255) / 256, 256, 0, stream>>>(rows, cols, vals,
                                                             startArr, bcnt, staged);
    k_fill_final<<<NUM_BKT, 256, 0, stream>>>(startArr, staged, edges);

    // layer 1: A -> B (writes every row; no memset needed)
    k_spmm_csr<<<(N_NODES + 3) / 4, 256, 0, stream>>>(startArr, counts, edges, tabA, tabB);
    k_gather_add<<<gGrid, 256, 0, stream>>>(users, items, tabB, vsel);

    // layer 2: B -> A
    k_spmm_csr<<<(N_NODES + 3) / 4, 256, 0, stream>>>(startArr, counts, edges, tabB, tabA);

    // layer 3 (selected rows only) fused with layer-2 gather_add
    k_spmm_sel<<<(2 * BATCH) / 4, 256, 0, stream>>>(users, items, startArr,
                                                    counts, edges, tabA, vsel);

    // MLP head
    k_mlp<<<1024, 256, 0, stream>>>(vsel, W0, b0, W1, b1, Wa, ba, out);
}

// Round 5
// 626.868 us; speedup vs baseline: 2.3756x; 2.3756x over previous
//
#include <hip/hip_runtime.h>
#include <math.h>

#define NUM_USERS 100000
#define NUM_ITEMS 50000
#define N_NODES   150000   // NUM_USERS + NUM_ITEMS
#define LATENT    64
#define N_EDGES   2400000
#define BATCH     16384
#define SCAN_BLK  1024
#define SCAN_GRID ((N_NODES + SCAN_BLK - 1) / SCAN_BLK)   // 147

// Per-layer rescale so fp8-quantized SpMM outputs stay in normal range.
// layer1 stored at x64, layer2 at x4096 (64^2).
#define LAYER_SCALE 64.0f

// ---------------------------------------------------------------------------
// fp8 e4m3fn helpers (software, RNE-ish; values are small/finite, no NaN/inf)
// ---------------------------------------------------------------------------
__device__ __forceinline__ unsigned char f2fp8(float f) {
    float a = fabsf(f);
    unsigned sign = (__float_as_uint(f) >> 24) & 0x80;
    if (a < 0x1p-10f) return (unsigned char)sign;           // below half min denormal -> 0
    if (a > 448.f) a = 448.f;                                // clamp (never expected)
    int e = (int)((__float_as_uint(a) >> 23) & 0xFF) - 127;  // floor(log2 a)
    if (e < -6) e = -6;                                      // denormal regime: step 2^-9
    float step = exp2f((float)(e - 3));
    float q = rintf(a / step) * step;                        // round to fp8 grid
    unsigned qu = __float_as_uint(q);
    int qe = (int)((qu >> 23) & 0xFF) - 127;
    if (qe < -6) {                                           // denormal: q = k * 2^-9
        return (unsigned char)(sign | (unsigned)(int)rintf(q * 512.0f));
    }
    unsigned qm = (qu >> 20) & 7;
    return (unsigned char)(sign | ((unsigned)(qe + 7) << 3) | qm);
}

__device__ __forceinline__ float fp82f(unsigned int b) {     // low 8 bits used
    unsigned s   = (b & 0x80) << 24;
    unsigned exp = (b >> 3) & 0xF;
    unsigned man = b & 7;
    float normal = __uint_as_float(s | ((exp + 120) << 23) | (man << 20));
    float dn = (float)(int)man * 0x1p-9f;
    dn = (b & 0x80) ? -dn : dn;
    return exp ? normal : dn;
}

// ---------------------------------------------------------------------------
// table = fp8(concat(user_emb, item_emb)), scale 1
// ---------------------------------------------------------------------------
__global__ void k_concat_fp8(const float4* __restrict__ ue,
                             const float4* __restrict__ ie,
                             uchar4* __restrict__ cur) {
    int i = blockIdx.x * blockDim.x + threadIdx.x;
    const int nU4 = NUM_USERS * (LATENT / 4);
    const int nT4 = N_NODES   * (LATENT / 4);
    if (i >= nT4) return;
    float4 v = (i < nU4) ? ue[i] : ie[i - nU4];
    uchar4 o;
    o.x = f2fp8(v.x); o.y = f2fp8(v.y); o.z = f2fp8(v.z); o.w = f2fp8(v.w);
    cur[i] = o;
}

// ---------------------------------------------------------------------------
// vsel[b, 0:64] = user_emb[users[b]] ; vsel[b,64:128] = item_emb[items[b]]
// (layer-0 kept exact fp32)
// ---------------------------------------------------------------------------
__global__ void k_sel_init(const int* __restrict__ users,
                           const int* __restrict__ items,
                           const float* __restrict__ ue,
                           const float* __restrict__ ie,
                           float* __restrict__ vsel) {
    int t = blockIdx.x * blockDim.x + threadIdx.x;
    int b = t >> 6, d = t & 63;
    vsel[b * 128 + d]      = ue[users[b] * 64 + d];
    vsel[b * 128 + 64 + d] = ie[items[b] * 64 + d];
}

// ---------------------------------------------------------------------------
// CSR build step 1: histogram of row degrees (150K counters -> ~16/counter,
// negligible same-address serialization @121ns/op)
// ---------------------------------------------------------------------------
__global__ void k_hist(const int* __restrict__ rows, int* __restrict__ counts) {
    int e = blockIdx.x * blockDim.x + threadIdx.x;
    if (e < N_EDGES) atomicAdd(&counts[rows[e]], 1);
}

// ---------------------------------------------------------------------------
// CSR build step 2: exclusive scan (3-phase)
// ---------------------------------------------------------------------------
__global__ __launch_bounds__(SCAN_BLK) void k_scan_a(const int* __restrict__ counts,
                                                     int* __restrict__ startArr,
                                                     int* __restrict__ bsum) {
    __shared__ int sh[SCAN_BLK];
    int i = blockIdx.x * SCAN_BLK + threadIdx.x;
    int v = (i < N_NODES) ? counts[i] : 0;
    sh[threadIdx.x] = v;
    __syncthreads();
    for (int off = 1; off < SCAN_BLK; off <<= 1) {
        int t = (threadIdx.x >= off) ? sh[threadIdx.x - off] : 0;
        __syncthreads();
        sh[threadIdx.x] += t;
        __syncthreads();
    }
    if (i < N_NODES) startArr[i] = sh[threadIdx.x] - v;           // exclusive
    if (threadIdx.x == SCAN_BLK - 1) bsum[blockIdx.x] = sh[threadIdx.x];
}

__global__ __launch_bounds__(256) void k_scan_b(int* __restrict__ bsum, int n) {
    __shared__ int sh[256];
    int v = (threadIdx.x < n) ? bsum[threadIdx.x] : 0;
    sh[threadIdx.x] = v;
    __syncthreads();
    for (int off = 1; off < 256; off <<= 1) {
        int t = (threadIdx.x >= off) ? sh[threadIdx.x - off] : 0;
        __syncthreads();
        sh[threadIdx.x] += t;
        __syncthreads();
    }
    if (threadIdx.x < n) bsum[threadIdx.x] = sh[threadIdx.x] - v; // exclusive
}

__global__ __launch_bounds__(SCAN_BLK) void k_scan_c(int* __restrict__ startArr,
                                                     const int* __restrict__ bsum) {
    int i = blockIdx.x * SCAN_BLK + threadIdx.x;
    if (i < N_NODES) startArr[i] += bsum[blockIdx.x];
}

// ---------------------------------------------------------------------------
// CSR build step 3: direct bucket fill (R3 design: per-row counters, low
// atomic contention; the 150MB scattered writeback is the known cost)
// ---------------------------------------------------------------------------
__global__ void k_fill(const int* __restrict__ rows, const int* __restrict__ cols,
                       const float* __restrict__ vals,
                       const int* __restrict__ startArr, int* __restrict__ cnt2,
                       int2* __restrict__ edges) {
    int e = blockIdx.x * blockDim.x + threadIdx.x;
    if (e < N_EDGES) {
        int r = rows[e];
        int p = startArr[r] + atomicAdd(&cnt2[r], 1);
        edges[p] = make_int2(cols[e], __float_as_int(vals[e]));
    }
}

// ---------------------------------------------------------------------------
// Gather SpMM (fp8 table): one wave per row, lane = latent dim, unroll 4.
// Wave gather = 64 consecutive bytes = one cacheline.
// Output stored at (input scale * LAYER_SCALE).
// ---------------------------------------------------------------------------
__global__ __launch_bounds__(256) void k_spmm_csr(const int* __restrict__ startArr,
                                                  const int* __restrict__ counts,
                                                  const int2* __restrict__ edges,
                                                  const unsigned char* __restrict__ cur,
                                                  unsigned char* __restrict__ nxt) {
    int row  = blockIdx.x * 4 + (threadIdx.x >> 6);
    int lane = threadIdx.x & 63;
    if (row >= N_NODES) return;
    row = __builtin_amdgcn_readfirstlane(row);
    int s = __builtin_amdgcn_readfirstlane(startArr[row]);
    int n = __builtin_amdgcn_readfirstlane(counts[row]);
    float acc = 0.f;
    int j = 0;
    for (; j + 4 <= n; j += 4) {
        int2 e0 = edges[s + j + 0];
        int2 e1 = edges[s + j + 1];
        int2 e2 = edges[s + j + 2];
        int2 e3 = edges[s + j + 3];
        float x0 = fp82f(cur[(size_t)e0.x * 64 + lane]);
        float x1 = fp82f(cur[(size_t)e1.x * 64 + lane]);
        float x2 = fp82f(cur[(size_t)e2.x * 64 + lane]);
        float x3 = fp82f(cur[(size_t)e3.x * 64 + lane]);
        acc = fmaf(__int_as_float(e0.y), x0, acc);
        acc = fmaf(__int_as_float(e1.y), x1, acc);
        acc = fmaf(__int_as_float(e2.y), x2, acc);
        acc = fmaf(__int_as_float(e3.y), x3, acc);
    }
    for (; j < n; j++) {
        int2 e = edges[s + j];
        acc = fmaf(__int_as_float(e.y), fp82f(cur[(size_t)e.x * 64 + lane]), acc);
    }
    nxt[(size_t)row * 64 + lane] = f2fp8(acc * LAYER_SCALE);
}

// ---------------------------------------------------------------------------
// Fused layer-3 + layer-2 gather_add at selected rows.
// cur = layer-2 output at scale 4096; both terms descaled by 1/4096.
// ---------------------------------------------------------------------------
__global__ __launch_bounds__(256) void k_spmm_sel(const int* __restrict__ users,
                                                  const int* __restrict__ items,
                                                  const int* __restrict__ startArr,
                                                  const int* __restrict__ counts,
                                                  const int2* __restrict__ edges,
                                                  const unsigned char* __restrict__ cur,
                                                  float* __restrict__ vsel) {
    int wave = blockIdx.x * 4 + (threadIdx.x >> 6);
    int lane = threadIdx.x & 63;
    int b, row;
    float* dst;
    if (wave < BATCH) {
        b = wave; row = users[b];
        dst = &vsel[b * 128 + lane];
    } else {
        b = wave - BATCH; row = NUM_USERS + items[b];
        dst = &vsel[b * 128 + 64 + lane];
    }
    int s = startArr[row];
    int n = counts[row];
    float acc = fp82f(cur[(size_t)row * 64 + lane]);   // layer-2 contribution
    int j = 0;
    for (; j + 4 <= n; j += 4) {
        int2 e0 = edges[s + j + 0];
        int2 e1 = edges[s + j + 1];
        int2 e2 = edges[s + j + 2];
        int2 e3 = edges[s + j + 3];
        float x0 = fp82f(cur[(size_t)e0.x * 64 + lane]);
        float x1 = fp82f(cur[(size_t)e1.x * 64 + lane]);
        float x2 = fp82f(cur[(size_t)e2.x * 64 + lane]);
        float x3 = fp82f(cur[(size_t)e3.x * 64 + lane]);
        acc = fmaf(__int_as_float(e0.y), x0, acc);
        acc = fmaf(__int_as_float(e1.y), x1, acc);
        acc = fmaf(__int_as_float(e2.y), x2, acc);
        acc = fmaf(__int_as_float(e3.y), x3, acc);
    }
    for (; j < n; j++) {
        int2 e = edges[s + j];
        acc = fmaf(__int_as_float(e.y), fp82f(cur[(size_t)e.x * 64 + lane]), acc);
    }
    *dst += acc * (1.0f / (LAYER_SCALE * LAYER_SCALE));
}

// ---------------------------------------------------------------------------
// vsel += src (fp8, scale 64) at selected rows — after layer 1
// ---------------------------------------------------------------------------
__global__ void k_gather_add(const int* __restrict__ users,
                             const int* __restrict__ items,
                             const unsigned char* __restrict__ src,
                             float* __restrict__ vsel) {
    int t = blockIdx.x * blockDim.x + threadIdx.x;
    int b = t >> 6, d = t & 63;
    vsel[b * 128 + d]      += fp82f(src[(size_t)users[b] * 64 + d]) * (1.0f / LAYER_SCALE);
    vsel[b * 128 + 64 + d] += fp82f(src[(size_t)(NUM_USERS + items[b]) * 64 + d]) * (1.0f / LAYER_SCALE);
}

// ---------------------------------------------------------------------------
// MLP head: one wave per batch row, weights in LDS.
// ---------------------------------------------------------------------------
__global__ __launch_bounds__(256) void k_mlp(const float* __restrict__ vsel,
                                             const float* __restrict__ W0,
                                             const float* __restrict__ b0,
                                             const float* __restrict__ W1,
                                             const float* __restrict__ b1,
                                             const float* __restrict__ Wa,
                                             const float* __restrict__ ba,
                                             float* __restrict__ out) {
    __shared__ float sW0[128 * 64];
    __shared__ float sW1[64 * 32];
    __shared__ float sWa[32];
    __shared__ float sb0[64];
    __shared__ float sb1[32];

    for (int i = threadIdx.x; i < 128 * 64; i += 256) sW0[i] = W0[i];
    for (int i = threadIdx.x; i < 64 * 32;  i += 256) sW1[i] = W1[i];
    if (threadIdx.x < 32) sWa[threadIdx.x] = Wa[threadIdx.x];
    if (threadIdx.x < 64) sb0[threadIdx.x] = b0[threadIdx.x];
    if (threadIdx.x >= 64 && threadIdx.x < 96) sb1[threadIdx.x - 64] = b1[threadIdx.x - 64];
    float sba = ba[0];
    __syncthreads();

    int lane   = threadIdx.x & 63;
    int wave   = blockIdx.x * (blockDim.x >> 6) + (threadIdx.x >> 6);
    int nwaves = gridDim.x * (blockDim.x >> 6);

    for (int b = wave; b < BATCH; b += nwaves) {
        float vlo = vsel[b * 128 + lane]      * 0.25f;
        float vhi = vsel[b * 128 + 64 + lane] * 0.25f;

        float h0 = 0.f;
        #pragma unroll
        for (int k = 0; k < 64; k++) {
            float a = __shfl(vlo, k);
            h0 = fmaf(a, sW0[k * 64 + lane], h0);
        }
        #pragma unroll
        for (int k = 0; k < 64; k++) {
            float a = __shfl(vhi, k);
            h0 = fmaf(a, sW0[(64 + k) * 64 + lane], h0);
        }
        h0 = fmaxf(h0 + sb0[lane], 0.f);

        float h1 = 0.f;
        #pragma unroll
        for (int k = 0; k < 64; k++) {
            float a = __shfl(h0, k);
            if (lane < 32) h1 = fmaf(a, sW1[k * 32 + lane], h1);
        }
        float contrib = 0.f;
        if (lane < 32) {
            h1 = fmaxf(h1 + sb1[lane], 0.f);
            contrib = h1 * sWa[lane];
        }
        #pragma unroll
        for (int off = 32; off > 0; off >>= 1)
            contrib += __shfl_down(contrib, off);

        if (lane == 0) {
            float logit = contrib + sba;
            out[b] = 1.0f / (1.0f + expf(-logit));
        }
    }
}

// ---------------------------------------------------------------------------
extern "C" void kernel_launch(void* const* d_in, const int* in_sizes, int n_in,
                              void* d_out, int out_size, void* d_ws, size_t ws_size,
                              hipStream_t stream) {
    const int*   users = (const int*)  d_in[0];
    const int*   items = (const int*)  d_in[1];
    const int*   rows  = (const int*)  d_in[2];
    const int*   cols  = (const int*)  d_in[3];
    const float* vals  = (const float*)d_in[4];
    const float* ue    = (const float*)d_in[5];
    const float* ie    = (const float*)d_in[6];
    const float* W0    = (const float*)d_in[7];
    const float* b0    = (const float*)d_in[8];
    const float* W1    = (const float*)d_in[9];
    const float* b1    = (const float*)d_in[10];
    const float* Wa    = (const float*)d_in[11];
    const float* ba    = (const float*)d_in[12];
    float* out = (float*)d_out;

    const size_t nodeElems = (size_t)N_NODES * LATENT;   // 9.6 M
    char* ws = (char*)d_ws;
    unsigned char* tabA = (unsigned char*)ws;  ws += nodeElems;                  // 9.6 MB
    unsigned char* tabB = (unsigned char*)ws;  ws += nodeElems;                  // 9.6 MB
    float* vsel = (float*)ws;                  ws += (size_t)BATCH * 128 * 4;    // 8.39 MB
    int2*  edges = (int2*)ws;                  ws += (size_t)N_EDGES * 8;        // 19.2 MB
    int* counts   = (int*)ws;                  ws += N_NODES * 4;
    int* startArr = (int*)ws;                  ws += N_NODES * 4;
    int* cnt2     = (int*)ws;                  ws += N_NODES * 4;
    int* bsum     = (int*)ws;                  ws += SCAN_GRID * 4;

    const int gGrid = (BATCH * 64) / 256;

    // fp8 table + fp32 layer-0 selection
    k_concat_fp8<<<(N_NODES * (LATENT / 4) + 255) / 256, 256, 0, stream>>>(
        (const float4*)ue, (const float4*)ie, (uchar4*)tabA);
    k_sel_init<<<gGrid, 256, 0, stream>>>(users, items, ue, ie, vsel);

    // ---- CSR build (R3 direct-fill design) ----
    hipMemsetAsync(counts, 0, N_NODES * 4, stream);
    hipMemsetAsync(cnt2,   0, N_NODES * 4, stream);
    k_hist<<<(N_EDGES + 255) / 256, 256, 0, stream>>>(rows, counts);
    k_scan_a<<<SCAN_GRID, SCAN_BLK, 0, stream>>>(counts, startArr, bsum);
    k_scan_b<<<1, 256, 0, stream>>>(bsum, SCAN_GRID);
    k_scan_c<<<SCAN_GRID, SCAN_BLK, 0, stream>>>(startArr, bsum);
    k_fill<<<(N_EDGES + 255) / 256, 256, 0, stream>>>(rows, cols, vals,
                                                      startArr, cnt2, edges);

    // layer 1: A -> B (writes every row; no memset needed)
    k_spmm_csr<<<(N_NODES + 3) / 4, 256, 0, stream>>>(startArr, counts, edges, tabA, tabB);
    k_gather_add<<<gGrid, 256, 0, stream>>>(users, items, tabB, vsel);

    // layer 2: B -> A
    k_spmm_csr<<<(N_NODES + 3) / 4, 256, 0, stream>>>(startArr, counts, edges, tabB, tabA);

    // layer 3 (selected rows only) fused with layer-2 gather_add
    k_spmm_sel<<<(2 * BATCH) / 4, 256, 0, stream>>>(users, items, startArr,
                                                    counts, edges, tabA, vsel);

    // MLP head
    k_mlp<<<1024, 256, 0, stream>>>(vsel, W0, b0, W1, b1, Wa, ba, out);
}

// Round 6
// 575.919 us; speedup vs baseline: 2.5858x; 1.0885x over previous
//
#include <hip/hip_runtime.h>
#include <math.h>

#define NUM_USERS 100000
#define NUM_ITEMS 50000
#define N_NODES   150000   // NUM_USERS + NUM_ITEMS
#define LATENT    64
#define N_EDGES   2400000
#define BATCH     16384
#define SCAN_BLK  1024
#define SCAN_GRID ((N_NODES + SCAN_BLK - 1) / SCAN_BLK)   // 147

// XCD-sharded fill windows: 8 windows x 18750 rows
#define NWIN      8
#define WIN_ROWS  18750

// bf16 helpers (values small/finite; RNE)
__device__ __forceinline__ unsigned short f2bf(float f) {
    unsigned u = __float_as_uint(f);
    u = (u + 0x7FFF + ((u >> 16) & 1)) >> 16;
    return (unsigned short)u;
}
__device__ __forceinline__ float bf2f(unsigned short h) {
    return __uint_as_float(((unsigned)h) << 16);
}

// ---------------------------------------------------------------------------
// table = bf16(concat(user_emb, item_emb))
// ---------------------------------------------------------------------------
__global__ void k_concat_bf16(const float4* __restrict__ ue,
                              const float4* __restrict__ ie,
                              ushort4* __restrict__ cur) {
    int i = blockIdx.x * blockDim.x + threadIdx.x;
    const int nU4 = NUM_USERS * (LATENT / 4);
    const int nT4 = N_NODES   * (LATENT / 4);
    if (i >= nT4) return;
    float4 v = (i < nU4) ? ue[i] : ie[i - nU4];
    ushort4 o;
    o.x = f2bf(v.x); o.y = f2bf(v.y); o.z = f2bf(v.z); o.w = f2bf(v.w);
    cur[i] = o;
}

// ---------------------------------------------------------------------------
// vsel[b, 0:64] = user_emb[users[b]] ; vsel[b,64:128] = item_emb[items[b]]
// ---------------------------------------------------------------------------
__global__ void k_sel_init(const int* __restrict__ users,
                           const int* __restrict__ items,
                           const float* __restrict__ ue,
                           const float* __restrict__ ie,
                           float* __restrict__ vsel) {
    int t = blockIdx.x * blockDim.x + threadIdx.x;
    int b = t >> 6, d = t & 63;
    vsel[b * 128 + d]      = ue[users[b] * 64 + d];
    vsel[b * 128 + 64 + d] = ie[items[b] * 64 + d];
}

// ---------------------------------------------------------------------------
// CSR build step 1: histogram (150K counters, ~16 hits each — fine at
// ~121ns/same-address atomic, measured R4)
// ---------------------------------------------------------------------------
__global__ void k_hist(const int* __restrict__ rows, int* __restrict__ counts) {
    int e = blockIdx.x * blockDim.x + threadIdx.x;
    if (e < N_EDGES) atomicAdd(&counts[rows[e]], 1);
}

// ---------------------------------------------------------------------------
// CSR build step 2: exclusive scan (3-phase)
// ---------------------------------------------------------------------------
__global__ __launch_bounds__(SCAN_BLK) void k_scan_a(const int* __restrict__ counts,
                                                     int* __restrict__ startArr,
                                                     int* __restrict__ bsum) {
    __shared__ int sh[SCAN_BLK];
    int i = blockIdx.x * SCAN_BLK + threadIdx.x;
    int v = (i < N_NODES) ? counts[i] : 0;
    sh[threadIdx.x] = v;
    __syncthreads();
    for (int off = 1; off < SCAN_BLK; off <<= 1) {
        int t = (threadIdx.x >= off) ? sh[threadIdx.x - off] : 0;
        __syncthreads();
        sh[threadIdx.x] += t;
        __syncthreads();
    }
    if (i < N_NODES) startArr[i] = sh[threadIdx.x] - v;           // exclusive
    if (threadIdx.x == SCAN_BLK - 1) bsum[blockIdx.x] = sh[threadIdx.x];
}

__global__ __launch_bounds__(256) void k_scan_b(int* __restrict__ bsum, int n) {
    __shared__ int sh[256];
    int v = (threadIdx.x < n) ? bsum[threadIdx.x] : 0;
    sh[threadIdx.x] = v;
    __syncthreads();
    for (int off = 1; off < 256; off <<= 1) {
        int t = (threadIdx.x >= off) ? sh[threadIdx.x - off] : 0;
        __syncthreads();
        sh[threadIdx.x] += t;
        __syncthreads();
    }
    if (threadIdx.x < n) bsum[threadIdx.x] = sh[threadIdx.x] - v; // exclusive
}

__global__ __launch_bounds__(SCAN_BLK) void k_scan_c(int* __restrict__ startArr,
                                                     const int* __restrict__ bsum) {
    int i = blockIdx.x * SCAN_BLK + threadIdx.x;
    if (i < N_NODES) startArr[i] += bsum[blockIdx.x];
}

// ---------------------------------------------------------------------------
// CSR fill, XCD-sharded windows: block handles only rows in window
// (blockIdx&7). With round-robin block->XCD placement, each 2.4MB output
// window is written by a single XCD's L2 -> lines fully dirty before
// writeback (merge). Correctness never depends on the mapping.
// ---------------------------------------------------------------------------
__global__ __launch_bounds__(256) void k_fill_win(const int* __restrict__ rows,
                                                  const int* __restrict__ cols,
                                                  const float* __restrict__ vals,
                                                  const int* __restrict__ startArr,
                                                  int* __restrict__ cnt2,
                                                  int2* __restrict__ edges) {
    const int myw = blockIdx.x & (NWIN - 1);
    const int lo  = myw * WIN_ROWS;
    const int hi  = lo + WIN_ROWS;
    const int group   = blockIdx.x >> 3;
    const int ngroups = gridDim.x >> 3;
    for (int e = group * 256 + threadIdx.x; e < N_EDGES; e += ngroups * 256) {
        int r = rows[e];
        if (r >= lo && r < hi) {
            int p = startArr[r] + atomicAdd(&cnt2[r], 1);
            edges[p] = make_int2(cols[e], __float_as_int(vals[e]));
        }
    }
}

// ---------------------------------------------------------------------------
// Gather SpMM (bf16): one wave per row, lane = dim. Unroll 8 for MLP
// (VGPR headroom is huge — R3 used only 8 VGPRs).
// ---------------------------------------------------------------------------
__global__ __launch_bounds__(256) void k_spmm_csr(const int* __restrict__ startArr,
                                                  const int* __restrict__ counts,
                                                  const int2* __restrict__ edges,
                                                  const unsigned short* __restrict__ cur,
                                                  unsigned short* __restrict__ nxt) {
    int row  = blockIdx.x * 4 + (threadIdx.x >> 6);
    int lane = threadIdx.x & 63;
    if (row >= N_NODES) return;
    row = __builtin_amdgcn_readfirstlane(row);
    int s = __builtin_amdgcn_readfirstlane(startArr[row]);
    int n = __builtin_amdgcn_readfirstlane(counts[row]);
    float acc = 0.f;
    int j = 0;
    for (; j + 8 <= n; j += 8) {
        int2 e0 = edges[s + j + 0];
        int2 e1 = edges[s + j + 1];
        int2 e2 = edges[s + j + 2];
        int2 e3 = edges[s + j + 3];
        int2 e4 = edges[s + j + 4];
        int2 e5 = edges[s + j + 5];
        int2 e6 = edges[s + j + 6];
        int2 e7 = edges[s + j + 7];
        float x0 = bf2f(cur[(size_t)e0.x * 64 + lane]);
        float x1 = bf2f(cur[(size_t)e1.x * 64 + lane]);
        float x2 = bf2f(cur[(size_t)e2.x * 64 + lane]);
        float x3 = bf2f(cur[(size_t)e3.x * 64 + lane]);
        float x4 = bf2f(cur[(size_t)e4.x * 64 + lane]);
        float x5 = bf2f(cur[(size_t)e5.x * 64 + lane]);
        float x6 = bf2f(cur[(size_t)e6.x * 64 + lane]);
        float x7 = bf2f(cur[(size_t)e7.x * 64 + lane]);
        acc = fmaf(__int_as_float(e0.y), x0, acc);
        acc = fmaf(__int_as_float(e1.y), x1, acc);
        acc = fmaf(__int_as_float(e2.y), x2, acc);
        acc = fmaf(__int_as_float(e3.y), x3, acc);
        acc = fmaf(__int_as_float(e4.y), x4, acc);
        acc = fmaf(__int_as_float(e5.y), x5, acc);
        acc = fmaf(__int_as_float(e6.y), x6, acc);
        acc = fmaf(__int_as_float(e7.y), x7, acc);
    }
    for (; j + 4 <= n; j += 4) {
        int2 e0 = edges[s + j + 0];
        int2 e1 = edges[s + j + 1];
        int2 e2 = edges[s + j + 2];
        int2 e3 = edges[s + j + 3];
        float x0 = bf2f(cur[(size_t)e0.x * 64 + lane]);
        float x1 = bf2f(cur[(size_t)e1.x * 64 + lane]);
        float x2 = bf2f(cur[(size_t)e2.x * 64 + lane]);
        float x3 = bf2f(cur[(size_t)e3.x * 64 + lane]);
        acc = fmaf(__int_as_float(e0.y), x0, acc);
        acc = fmaf(__int_as_float(e1.y), x1, acc);
        acc = fmaf(__int_as_float(e2.y), x2, acc);
        acc = fmaf(__int_as_float(e3.y), x3, acc);
    }
    for (; j < n; j++) {
        int2 e = edges[s + j];
        acc = fmaf(__int_as_float(e.y), bf2f(cur[(size_t)e.x * 64 + lane]), acc);
    }
    nxt[(size_t)row * 64 + lane] = f2bf(acc);
}

// ---------------------------------------------------------------------------
// Fused layer-3 + layer-2 gather_add at selected rows.
// ---------------------------------------------------------------------------
__global__ __launch_bounds__(256) void k_spmm_sel(const int* __restrict__ users,
                                                  const int* __restrict__ items,
                                                  const int* __restrict__ startArr,
                                                  const int* __restrict__ counts,
                                                  const int2* __restrict__ edges,
                                                  const unsigned short* __restrict__ cur,
                                                  float* __restrict__ vsel) {
    int wave = blockIdx.x * 4 + (threadIdx.x >> 6);
    int lane = threadIdx.x & 63;
    int b, row;
    float* dst;
    if (wave < BATCH) {
        b = wave; row = users[b];
        dst = &vsel[b * 128 + lane];
    } else {
        b = wave - BATCH; row = NUM_USERS + items[b];
        dst = &vsel[b * 128 + 64 + lane];
    }
    int s = startArr[row];
    int n = counts[row];
    float acc = bf2f(cur[(size_t)row * 64 + lane]);   // layer-2 contribution
    int j = 0;
    for (; j + 8 <= n; j += 8) {
        int2 e0 = edges[s + j + 0];
        int2 e1 = edges[s + j + 1];
        int2 e2 = edges[s + j + 2];
        int2 e3 = edges[s + j + 3];
        int2 e4 = edges[s + j + 4];
        int2 e5 = edges[s + j + 5];
        int2 e6 = edges[s + j + 6];
        int2 e7 = edges[s + j + 7];
        float x0 = bf2f(cur[(size_t)e0.x * 64 + lane]);
        float x1 = bf2f(cur[(size_t)e1.x * 64 + lane]);
        float x2 = bf2f(cur[(size_t)e2.x * 64 + lane]);
        float x3 = bf2f(cur[(size_t)e3.x * 64 + lane]);
        float x4 = bf2f(cur[(size_t)e4.x * 64 + lane]);
        float x5 = bf2f(cur[(size_t)e5.x * 64 + lane]);
        float x6 = bf2f(cur[(size_t)e6.x * 64 + lane]);
        float x7 = bf2f(cur[(size_t)e7.x * 64 + lane]);
        acc = fmaf(__int_as_float(e0.y), x0, acc);
        acc = fmaf(__int_as_float(e1.y), x1, acc);
        acc = fmaf(__int_as_float(e2.y), x2, acc);
        acc = fmaf(__int_as_float(e3.y), x3, acc);
        acc = fmaf(__int_as_float(e4.y), x4, acc);
        acc = fmaf(__int_as_float(e5.y), x5, acc);
        acc = fmaf(__int_as_float(e6.y), x6, acc);
        acc = fmaf(__int_as_float(e7.y), x7, acc);
    }
    for (; j + 4 <= n; j += 4) {
        int2 e0 = edges[s + j + 0];
        int2 e1 = edges[s + j + 1];
        int2 e2 = edges[s + j + 2];
        int2 e3 = edges[s + j + 3];
        float x0 = bf2f(cur[(size_t)e0.x * 64 + lane]);
        float x1 = bf2f(cur[(size_t)e1.x * 64 + lane]);
        float x2 = bf2f(cur[(size_t)e2.x * 64 + lane]);
        float x3 = bf2f(cur[(size_t)e3.x * 64 + lane]);
        acc = fmaf(__int_as_float(e0.y), x0, acc);
        acc = fmaf(__int_as_float(e1.y), x1, acc);
        acc = fmaf(__int_as_float(e2.y), x2, acc);
        acc = fmaf(__int_as_float(e3.y), x3, acc);
    }
    for (; j < n; j++) {
        int2 e = edges[s + j];
        acc = fmaf(__int_as_float(e.y), bf2f(cur[(size_t)e.x * 64 + lane]), acc);
    }
    *dst += acc;
}

// ---------------------------------------------------------------------------
// vsel += bf16 src at selected rows (after layer 1)
// ---------------------------------------------------------------------------
__global__ void k_gather_add(const int* __restrict__ users,
                             const int* __restrict__ items,
                             const unsigned short* __restrict__ src,
                             float* __restrict__ vsel) {
    int t = blockIdx.x * blockDim.x + threadIdx.x;
    int b = t >> 6, d = t & 63;
    vsel[b * 128 + d]      += bf2f(src[(size_t)users[b] * 64 + d]);
    vsel[b * 128 + 64 + d] += bf2f(src[(size_t)(NUM_USERS + items[b]) * 64 + d]);
}

// ---------------------------------------------------------------------------
// MLP head: one wave per batch row, weights in LDS.
// ---------------------------------------------------------------------------
__global__ __launch_bounds__(256) void k_mlp(const float* __restrict__ vsel,
                                             const float* __restrict__ W0,
                                             const float* __restrict__ b0,
                                             const float* __restrict__ W1,
                                             const float* __restrict__ b1,
                                             const float* __restrict__ Wa,
                                             const float* __restrict__ ba,
                                             float* __restrict__ out) {
    __shared__ float sW0[128 * 64];
    __shared__ float sW1[64 * 32];
    __shared__ float sWa[32];
    __shared__ float sb0[64];
    __shared__ float sb1[32];

    for (int i = threadIdx.x; i < 128 * 64; i += 256) sW0[i] = W0[i];
    for (int i = threadIdx.x; i < 64 * 32;  i += 256) sW1[i] = W1[i];
    if (threadIdx.x < 32) sWa[threadIdx.x] = Wa[threadIdx.x];
    if (threadIdx.x < 64) sb0[threadIdx.x] = b0[threadIdx.x];
    if (threadIdx.x >= 64 && threadIdx.x < 96) sb1[threadIdx.x - 64] = b1[threadIdx.x - 64];
    float sba = ba[0];
    __syncthreads();

    int lane   = threadIdx.x & 63;
    int wave   = blockIdx.x * (blockDim.x >> 6) + (threadIdx.x >> 6);
    int nwaves = gridDim.x * (blockDim.x >> 6);

    for (int b = wave; b < BATCH; b += nwaves) {
        float vlo = vsel[b * 128 + lane]      * 0.25f;
        float vhi = vsel[b * 128 + 64 + lane] * 0.25f;

        float h0 = 0.f;
        #pragma unroll
        for (int k = 0; k < 64; k++) {
            float a = __shfl(vlo, k);
            h0 = fmaf(a, sW0[k * 64 + lane], h0);
        }
        #pragma unroll
        for (int k = 0; k < 64; k++) {
            float a = __shfl(vhi, k);
            h0 = fmaf(a, sW0[(64 + k) * 64 + lane], h0);
        }
        h0 = fmaxf(h0 + sb0[lane], 0.f);

        float h1 = 0.f;
        #pragma unroll
        for (int k = 0; k < 64; k++) {
            float a = __shfl(h0, k);
            if (lane < 32) h1 = fmaf(a, sW1[k * 32 + lane], h1);
        }
        float contrib = 0.f;
        if (lane < 32) {
            h1 = fmaxf(h1 + sb1[lane], 0.f);
            contrib = h1 * sWa[lane];
        }
        #pragma unroll
        for (int off = 32; off > 0; off >>= 1)
            contrib += __shfl_down(contrib, off);

        if (lane == 0) {
            float logit = contrib + sba;
            out[b] = 1.0f / (1.0f + expf(-logit));
        }
    }
}

// ---------------------------------------------------------------------------
extern "C" void kernel_launch(void* const* d_in, const int* in_sizes, int n_in,
                              void* d_out, int out_size, void* d_ws, size_t ws_size,
                              hipStream_t stream) {
    const int*   users = (const int*)  d_in[0];
    const int*   items = (const int*)  d_in[1];
    const int*   rows  = (const int*)  d_in[2];
    const int*   cols  = (const int*)  d_in[3];
    const float* vals  = (const float*)d_in[4];
    const float* ue    = (const float*)d_in[5];
    const float* ie    = (const float*)d_in[6];
    const float* W0    = (const float*)d_in[7];
    const float* b0    = (const float*)d_in[8];
    const float* W1    = (const float*)d_in[9];
    const float* b1    = (const float*)d_in[10];
    const float* Wa    = (const float*)d_in[11];
    const float* ba    = (const float*)d_in[12];
    float* out = (float*)d_out;

    const size_t nodeElems = (size_t)N_NODES * LATENT;   // 9.6 M
    char* ws = (char*)d_ws;
    unsigned short* tabA = (unsigned short*)ws;  ws += nodeElems * 2;            // 19.2 MB
    unsigned short* tabB = (unsigned short*)ws;  ws += nodeElems * 2;            // 19.2 MB
    float* vsel = (float*)ws;                    ws += (size_t)BATCH * 128 * 4;  // 8.39 MB
    int2*  edges = (int2*)ws;                    ws += (size_t)N_EDGES * 8;      // 19.2 MB
    int* counts   = (int*)ws;                    ws += N_NODES * 4;
    int* startArr = (int*)ws;                    ws += N_NODES * 4;
    int* cnt2     = (int*)ws;                    ws += N_NODES * 4;
    int* bsum     = (int*)ws;                    ws += SCAN_GRID * 4;

    const int gGrid = (BATCH * 64) / 256;

    // bf16 table + fp32 layer-0 selection
    k_concat_bf16<<<(N_NODES * (LATENT / 4) + 255) / 256, 256, 0, stream>>>(
        (const float4*)ue, (const float4*)ie, (ushort4*)tabA);
    k_sel_init<<<gGrid, 256, 0, stream>>>(users, items, ue, ie, vsel);

    // ---- CSR build ----
    hipMemsetAsync(counts, 0, N_NODES * 4, stream);
    hipMemsetAsync(cnt2,   0, N_NODES * 4, stream);
    k_hist<<<(N_EDGES + 255) / 256, 256, 0, stream>>>(rows, counts);
    k_scan_a<<<SCAN_GRID, SCAN_BLK, 0, stream>>>(counts, startArr, bsum);
    k_scan_b<<<1, 256, 0, stream>>>(bsum, SCAN_GRID);
    k_scan_c<<<SCAN_GRID, SCAN_BLK, 0, stream>>>(startArr, bsum);
    k_fill_win<<<4096, 256, 0, stream>>>(rows, cols, vals, startArr, cnt2, edges);

    // layer 1: A -> B (writes every row; no memset needed)
    k_spmm_csr<<<(N_NODES + 3) / 4, 256, 0, stream>>>(startArr, counts, edges, tabA, tabB);
    k_gather_add<<<gGrid, 256, 0, stream>>>(users, items, tabB, vsel);

    // layer 2: B -> A
    k_spmm_csr<<<(N_NODES + 3) / 4, 256, 0, stream>>>(startArr, counts, edges, tabB, tabA);

    // layer 3 (selected rows only) fused with layer-2 gather_add
    k_spmm_sel<<<(2 * BATCH) / 4, 256, 0, stream>>>(users, items, startArr,
                                                    counts, edges, tabA, vsel);

    // MLP head
    k_mlp<<<1024, 256, 0, stream>>>(vsel, W0, b0, W1, b1, Wa, ba, out);
}

// Round 7
// 505.194 us; speedup vs baseline: 2.9478x; 1.1400x over previous
//
#include <hip/hip_runtime.h>
#include <math.h>

#define NUM_USERS 100000
#define NUM_ITEMS 50000
#define N_NODES   150000   // NUM_USERS + NUM_ITEMS
#define LATENT    64
#define N_EDGES   2400000
#define BATCH     16384
#define SCAN_BLK  1024
#define SCAN_GRID ((N_NODES + SCAN_BLK - 1) / SCAN_BLK)   // 147

// Multisplit fill: 4096-edge chunks, 512-row buckets
#define CHUNK 4096
#define NBLK  ((N_EDGES + CHUNK - 1) / CHUNK)   // 586
#define NBKT  ((N_NODES + 511) / 512)           // 293

// bf16 helpers (values small/finite; RNE)
__device__ __forceinline__ unsigned short f2bf(float f) {
    unsigned u = __float_as_uint(f);
    u = (u + 0x7FFF + ((u >> 16) & 1)) >> 16;
    return (unsigned short)u;
}
__device__ __forceinline__ float bf2f(unsigned short h) {
    return __uint_as_float(((unsigned)h) << 16);
}

// ---------------------------------------------------------------------------
// table = bf16(concat(user_emb, item_emb))
// ---------------------------------------------------------------------------
__global__ void k_concat_bf16(const float4* __restrict__ ue,
                              const float4* __restrict__ ie,
                              ushort4* __restrict__ cur) {
    int i = blockIdx.x * blockDim.x + threadIdx.x;
    const int nU4 = NUM_USERS * (LATENT / 4);
    const int nT4 = N_NODES   * (LATENT / 4);
    if (i >= nT4) return;
    float4 v = (i < nU4) ? ue[i] : ie[i - nU4];
    ushort4 o;
    o.x = f2bf(v.x); o.y = f2bf(v.y); o.z = f2bf(v.z); o.w = f2bf(v.w);
    cur[i] = o;
}

// ---------------------------------------------------------------------------
// vsel[b, 0:64] = user_emb[users[b]] ; vsel[b,64:128] = item_emb[items[b]]
// ---------------------------------------------------------------------------
__global__ void k_sel_init(const int* __restrict__ users,
                           const int* __restrict__ items,
                           const float* __restrict__ ue,
                           const float* __restrict__ ie,
                           float* __restrict__ vsel) {
    int t = blockIdx.x * blockDim.x + threadIdx.x;
    int b = t >> 6, d = t & 63;
    vsel[b * 128 + d]      = ue[users[b] * 64 + d];
    vsel[b * 128 + 64 + d] = ie[items[b] * 64 + d];
}

// ---------------------------------------------------------------------------
// Row-degree histogram (for counts + startArr)
// ---------------------------------------------------------------------------
__global__ void k_hist(const int* __restrict__ rows, int* __restrict__ counts) {
    int e = blockIdx.x * blockDim.x + threadIdx.x;
    if (e < N_EDGES) atomicAdd(&counts[rows[e]], 1);
}

// ---------------------------------------------------------------------------
// Exclusive scan of counts -> startArr (3-phase)
// ---------------------------------------------------------------------------
__global__ __launch_bounds__(SCAN_BLK) void k_scan_a(const int* __restrict__ counts,
                                                     int* __restrict__ startArr,
                                                     int* __restrict__ bsum) {
    __shared__ int sh[SCAN_BLK];
    int i = blockIdx.x * SCAN_BLK + threadIdx.x;
    int v = (i < N_NODES) ? counts[i] : 0;
    sh[threadIdx.x] = v;
    __syncthreads();
    for (int off = 1; off < SCAN_BLK; off <<= 1) {
        int t = (threadIdx.x >= off) ? sh[threadIdx.x - off] : 0;
        __syncthreads();
        sh[threadIdx.x] += t;
        __syncthreads();
    }
    if (i < N_NODES) startArr[i] = sh[threadIdx.x] - v;           // exclusive
    if (threadIdx.x == SCAN_BLK - 1) bsum[blockIdx.x] = sh[threadIdx.x];
}

__global__ __launch_bounds__(256) void k_scan_b(int* __restrict__ bsum, int n) {
    __shared__ int sh[256];
    int v = (threadIdx.x < n) ? bsum[threadIdx.x] : 0;
    sh[threadIdx.x] = v;
    __syncthreads();
    for (int off = 1; off < 256; off <<= 1) {
        int t = (threadIdx.x >= off) ? sh[threadIdx.x - off] : 0;
        __syncthreads();
        sh[threadIdx.x] += t;
        __syncthreads();
    }
    if (threadIdx.x < n) bsum[threadIdx.x] = sh[threadIdx.x] - v; // exclusive
}

__global__ __launch_bounds__(SCAN_BLK) void k_scan_c(int* __restrict__ startArr,
                                                     const int* __restrict__ bsum) {
    int i = blockIdx.x * SCAN_BLK + threadIdx.x;
    if (i < N_NODES) startArr[i] += bsum[blockIdx.x];
}

// ---------------------------------------------------------------------------
// Multisplit p1a: per-block bucket histogram -> cmat[bucket][block]
// ---------------------------------------------------------------------------
__global__ __launch_bounds__(256) void k_p1a(const int* __restrict__ rows,
                                             int* __restrict__ cmat) {
    __shared__ int hist[NBKT];
    for (int i = threadIdx.x; i < NBKT; i += 256) hist[i] = 0;
    __syncthreads();
    int e0 = blockIdx.x * CHUNK;
    int cnt = min(CHUNK, N_EDGES - e0);
    for (int t = threadIdx.x; t < cnt; t += 256)
        atomicAdd(&hist[rows[e0 + t] >> 9], 1);
    __syncthreads();
    for (int i = threadIdx.x; i < NBKT; i += 256)
        cmat[i * NBLK + blockIdx.x] = hist[i];
}

// ---------------------------------------------------------------------------
// Multisplit p1b: per-bucket exclusive scan over blocks + bucket base.
// cmat row k becomes exact global write offsets for each block's run.
// ---------------------------------------------------------------------------
__global__ __launch_bounds__(1024) void k_p1b(const int* __restrict__ startArr,
                                              int* __restrict__ cmat) {
    __shared__ int sh[1024];
    int k = blockIdx.x;
    int v = (threadIdx.x < NBLK) ? cmat[k * NBLK + threadIdx.x] : 0;
    sh[threadIdx.x] = v;
    __syncthreads();
    for (int off = 1; off < 1024; off <<= 1) {
        int t = (threadIdx.x >= off) ? sh[threadIdx.x - off] : 0;
        __syncthreads();
        sh[threadIdx.x] += t;
        __syncthreads();
    }
    int base = startArr[k << 9];
    if (threadIdx.x < NBLK)
        cmat[k * NBLK + threadIdx.x] = base + sh[threadIdx.x] - v;
}

// ---------------------------------------------------------------------------
// Multisplit p1c: re-read chunk, bin records in LDS, flush bucket-contiguous
// runs at exact offsets. Zero global atomics; coalesced run writes.
// Record: x = col(18b) | rowLo(9b)<<18 ; y = fp32 val bits.
// ---------------------------------------------------------------------------
__global__ __launch_bounds__(256) void k_p1c(const int* __restrict__ rows,
                                             const int* __restrict__ cols,
                                             const float* __restrict__ vals,
                                             const int* __restrict__ offs,
                                             int2* __restrict__ staged) {
    __shared__ int hist[NBKT];
    __shared__ int lstart[NBKT];
    __shared__ int cursor[NBKT];
    __shared__ int soffs[NBKT];
    __shared__ int sc[512];
    __shared__ int2 st[CHUNK];
    __shared__ unsigned short bkt16[CHUNK];

    int e0 = blockIdx.x * CHUNK;
    int cnt = min(CHUNK, N_EDGES - e0);
    for (int i = threadIdx.x; i < NBKT; i += 256) {
        hist[i] = 0; cursor[i] = 0;
        soffs[i] = offs[i * NBLK + blockIdx.x];
    }
    sc[threadIdx.x] = 0; sc[threadIdx.x + 256] = 0;
    __syncthreads();
    for (int t = threadIdx.x; t < cnt; t += 256)
        atomicAdd(&hist[rows[e0 + t] >> 9], 1);
    __syncthreads();
    for (int i = threadIdx.x; i < NBKT; i += 256) sc[i] = hist[i];
    __syncthreads();
    // inclusive scan over 512 slots, 256 threads x 2 elems (Hillis-Steele)
    for (int off = 1; off < 512; off <<= 1) {
        int a0 = (threadIdx.x >= off)       ? sc[threadIdx.x - off]       : 0;
        int a1 = (threadIdx.x + 256 >= off) ? sc[threadIdx.x + 256 - off] : 0;
        __syncthreads();
        sc[threadIdx.x]       += a0;
        sc[threadIdx.x + 256] += a1;
        __syncthreads();
    }
    for (int i = threadIdx.x; i < NBKT; i += 256) lstart[i] = sc[i] - hist[i];
    __syncthreads();
    // bin into LDS staging
    for (int t = threadIdx.x; t < cnt; t += 256) {
        int r = rows[e0 + t];
        int b = r >> 9;
        int p = lstart[b] + atomicAdd(&cursor[b], 1);
        st[p] = make_int2(cols[e0 + t] | ((r & 511) << 18),
                          __float_as_int(vals[e0 + t]));
        bkt16[p] = (unsigned short)b;
    }
    __syncthreads();
    // flush: consecutive threads in a bucket write consecutive global addrs
    for (int t = threadIdx.x; t < cnt; t += 256) {
        int b = bkt16[t];
        staged[soffs[b] + (t - lstart[b])] = st[t];
    }
}

// ---------------------------------------------------------------------------
// Multisplit p2: one block per bucket; row-local placement via LDS counters.
// All writes land in the bucket's ~65KB contiguous window -> full-line merge.
// ---------------------------------------------------------------------------
__global__ __launch_bounds__(256) void k_p2(const int* __restrict__ startArr,
                                            const int2* __restrict__ staged,
                                            int2* __restrict__ edges) {
    __shared__ int sStart[512];
    __shared__ int sCnt[512];
    int k = blockIdx.x;
    int rowBase = k << 9;
    int numRows = min(512, N_NODES - rowBase);
    int base = startArr[rowBase];
    int end  = (k == NBKT - 1) ? N_EDGES : startArr[rowBase + 512];
    for (int i = threadIdx.x; i < numRows; i += 256) {
        sStart[i] = startArr[rowBase + i] - base;
        sCnt[i]   = 0;
    }
    __syncthreads();
    int cnt = end - base;
    for (int t = threadIdx.x; t < cnt; t += 256) {
        int2 rec = staged[base + t];
        int rl = ((unsigned)rec.x) >> 18;
        int c  = rec.x & 0x3FFFF;
        int off = sStart[rl] + atomicAdd(&sCnt[rl], 1);
        edges[base + off] = make_int2(c, rec.y);
    }
}

// ---------------------------------------------------------------------------
// Gather SpMM (bf16): one wave per row, lane = dim, unroll 8.
// ---------------------------------------------------------------------------
__global__ __launch_bounds__(256) void k_spmm_csr(const int* __restrict__ startArr,
                                                  const int* __restrict__ counts,
                                                  const int2* __restrict__ edges,
                                                  const unsigned short* __restrict__ cur,
                                                  unsigned short* __restrict__ nxt) {
    int row  = blockIdx.x * 4 + (threadIdx.x >> 6);
    int lane = threadIdx.x & 63;
    if (row >= N_NODES) return;
    row = __builtin_amdgcn_readfirstlane(row);
    int s = __builtin_amdgcn_readfirstlane(startArr[row]);
    int n = __builtin_amdgcn_readfirstlane(counts[row]);
    float acc = 0.f;
    int j = 0;
    for (; j + 8 <= n; j += 8) {
        int2 e0 = edges[s + j + 0];
        int2 e1 = edges[s + j + 1];
        int2 e2 = edges[s + j + 2];
        int2 e3 = edges[s + j + 3];
        int2 e4 = edges[s + j + 4];
        int2 e5 = edges[s + j + 5];
        int2 e6 = edges[s + j + 6];
        int2 e7 = edges[s + j + 7];
        float x0 = bf2f(cur[(size_t)e0.x * 64 + lane]);
        float x1 = bf2f(cur[(size_t)e1.x * 64 + lane]);
        float x2 = bf2f(cur[(size_t)e2.x * 64 + lane]);
        float x3 = bf2f(cur[(size_t)e3.x * 64 + lane]);
        float x4 = bf2f(cur[(size_t)e4.x * 64 + lane]);
        float x5 = bf2f(cur[(size_t)e5.x * 64 + lane]);
        float x6 = bf2f(cur[(size_t)e6.x * 64 + lane]);
        float x7 = bf2f(cur[(size_t)e7.x * 64 + lane]);
        acc = fmaf(__int_as_float(e0.y), x0, acc);
        acc = fmaf(__int_as_float(e1.y), x1, acc);
        acc = fmaf(__int_as_float(e2.y), x2, acc);
        acc = fmaf(__int_as_float(e3.y), x3, acc);
        acc = fmaf(__int_as_float(e4.y), x4, acc);
        acc = fmaf(__int_as_float(e5.y), x5, acc);
        acc = fmaf(__int_as_float(e6.y), x6, acc);
        acc = fmaf(__int_as_float(e7.y), x7, acc);
    }
    for (; j + 4 <= n; j += 4) {
        int2 e0 = edges[s + j + 0];
        int2 e1 = edges[s + j + 1];
        int2 e2 = edges[s + j + 2];
        int2 e3 = edges[s + j + 3];
        float x0 = bf2f(cur[(size_t)e0.x * 64 + lane]);
        float x1 = bf2f(cur[(size_t)e1.x * 64 + lane]);
        float x2 = bf2f(cur[(size_t)e2.x * 64 + lane]);
        float x3 = bf2f(cur[(size_t)e3.x * 64 + lane]);
        acc = fmaf(__int_as_float(e0.y), x0, acc);
        acc = fmaf(__int_as_float(e1.y), x1, acc);
        acc = fmaf(__int_as_float(e2.y), x2, acc);
        acc = fmaf(__int_as_float(e3.y), x3, acc);
    }
    for (; j < n; j++) {
        int2 e = edges[s + j];
        acc = fmaf(__int_as_float(e.y), bf2f(cur[(size_t)e.x * 64 + lane]), acc);
    }
    nxt[(size_t)row * 64 + lane] = f2bf(acc);
}

// ---------------------------------------------------------------------------
// Fused layer-3 + layer-2 gather_add at selected rows.
// ---------------------------------------------------------------------------
__global__ __launch_bounds__(256) void k_spmm_sel(const int* __restrict__ users,
                                                  const int* __restrict__ items,
                                                  const int* __restrict__ startArr,
                                                  const int* __restrict__ counts,
                                                  const int2* __restrict__ edges,
                                                  const unsigned short* __restrict__ cur,
                                                  float* __restrict__ vsel) {
    int wave = blockIdx.x * 4 + (threadIdx.x >> 6);
    int lane = threadIdx.x & 63;
    int b, row;
    float* dst;
    if (wave < BATCH) {
        b = wave; row = users[b];
        dst = &vsel[b * 128 + lane];
    } else {
        b = wave - BATCH; row = NUM_USERS + items[b];
        dst = &vsel[b * 128 + 64 + lane];
    }
    int s = startArr[row];
    int n = counts[row];
    float acc = bf2f(cur[(size_t)row * 64 + lane]);   // layer-2 contribution
    int j = 0;
    for (; j + 8 <= n; j += 8) {
        int2 e0 = edges[s + j + 0];
        int2 e1 = edges[s + j + 1];
        int2 e2 = edges[s + j + 2];
        int2 e3 = edges[s + j + 3];
        int2 e4 = edges[s + j + 4];
        int2 e5 = edges[s + j + 5];
        int2 e6 = edges[s + j + 6];
        int2 e7 = edges[s + j + 7];
        float x0 = bf2f(cur[(size_t)e0.x * 64 + lane]);
        float x1 = bf2f(cur[(size_t)e1.x * 64 + lane]);
        float x2 = bf2f(cur[(size_t)e2.x * 64 + lane]);
        float x3 = bf2f(cur[(size_t)e3.x * 64 + lane]);
        float x4 = bf2f(cur[(size_t)e4.x * 64 + lane]);
        float x5 = bf2f(cur[(size_t)e5.x * 64 + lane]);
        float x6 = bf2f(cur[(size_t)e6.x * 64 + lane]);
        float x7 = bf2f(cur[(size_t)e7.x * 64 + lane]);
        acc = fmaf(__int_as_float(e0.y), x0, acc);
        acc = fmaf(__int_as_float(e1.y), x1, acc);
        acc = fmaf(__int_as_float(e2.y), x2, acc);
        acc = fmaf(__int_as_float(e3.y), x3, acc);
        acc = fmaf(__int_as_float(e4.y), x4, acc);
        acc = fmaf(__int_as_float(e5.y), x5, acc);
        acc = fmaf(__int_as_float(e6.y), x6, acc);
        acc = fmaf(__int_as_float(e7.y), x7, acc);
    }
    for (; j + 4 <= n; j += 4) {
        int2 e0 = edges[s + j + 0];
        int2 e1 = edges[s + j + 1];
        int2 e2 = edges[s + j + 2];
        int2 e3 = edges[s + j + 3];
        float x0 = bf2f(cur[(size_t)e0.x * 64 + lane]);
        float x1 = bf2f(cur[(size_t)e1.x * 64 + lane]);
        float x2 = bf2f(cur[(size_t)e2.x * 64 + lane]);
        float x3 = bf2f(cur[(size_t)e3.x * 64 + lane]);
        acc = fmaf(__int_as_float(e0.y), x0, acc);
        acc = fmaf(__int_as_float(e1.y), x1, acc);
        acc = fmaf(__int_as_float(e2.y), x2, acc);
        acc = fmaf(__int_as_float(e3.y), x3, acc);
    }
    for (; j < n; j++) {
        int2 e = edges[s + j];
        acc = fmaf(__int_as_float(e.y), bf2f(cur[(size_t)e.x * 64 + lane]), acc);
    }
    *dst += acc;
}

// ---------------------------------------------------------------------------
// vsel += bf16 src at selected rows (after layer 1)
// ---------------------------------------------------------------------------
__global__ void k_gather_add(const int* __restrict__ users,
                             const int* __restrict__ items,
                             const unsigned short* __restrict__ src,
                             float* __restrict__ vsel) {
    int t = blockIdx.x * blockDim.x + threadIdx.x;
    int b = t >> 6, d = t & 63;
    vsel[b * 128 + d]      += bf2f(src[(size_t)users[b] * 64 + d]);
    vsel[b * 128 + 64 + d] += bf2f(src[(size_t)(NUM_USERS + items[b]) * 64 + d]);
}

// ---------------------------------------------------------------------------
// MLP head: one wave per batch row, weights in LDS.
// ---------------------------------------------------------------------------
__global__ __launch_bounds__(256) void k_mlp(const float* __restrict__ vsel,
                                             const float* __restrict__ W0,
                                             const float* __restrict__ b0,
                                             const float* __restrict__ W1,
                                             const float* __restrict__ b1,
                                             const float* __restrict__ Wa,
                                             const float* __restrict__ ba,
                                             float* __restrict__ out) {
    __shared__ float sW0[128 * 64];
    __shared__ float sW1[64 * 32];
    __shared__ float sWa[32];
    __shared__ float sb0[64];
    __shared__ float sb1[32];

    for (int i = threadIdx.x; i < 128 * 64; i += 256) sW0[i] = W0[i];
    for (int i = threadIdx.x; i < 64 * 32;  i += 256) sW1[i] = W1[i];
    if (threadIdx.x < 32) sWa[threadIdx.x] = Wa[threadIdx.x];
    if (threadIdx.x < 64) sb0[threadIdx.x] = b0[threadIdx.x];
    if (threadIdx.x >= 64 && threadIdx.x < 96) sb1[threadIdx.x - 64] = b1[threadIdx.x - 64];
    float sba = ba[0];
    __syncthreads();

    int lane   = threadIdx.x & 63;
    int wave   = blockIdx.x * (blockDim.x >> 6) + (threadIdx.x >> 6);
    int nwaves = gridDim.x * (blockDim.x >> 6);

    for (int b = wave; b < BATCH; b += nwaves) {
        float vlo = vsel[b * 128 + lane]      * 0.25f;
        float vhi = vsel[b * 128 + 64 + lane] * 0.25f;

        float h0 = 0.f;
        #pragma unroll
        for (int k = 0; k < 64; k++) {
            float a = __shfl(vlo, k);
            h0 = fmaf(a, sW0[k * 64 + lane], h0);
        }
        #pragma unroll
        for (int k = 0; k < 64; k++) {
            float a = __shfl(vhi, k);
            h0 = fmaf(a, sW0[(64 + k) * 64 + lane], h0);
        }
        h0 = fmaxf(h0 + sb0[lane], 0.f);

        float h1 = 0.f;
        #pragma unroll
        for (int k = 0; k < 64; k++) {
            float a = __shfl(h0, k);
            if (lane < 32) h1 = fmaf(a, sW1[k * 32 + lane], h1);
        }
        float contrib = 0.f;
        if (lane < 32) {
            h1 = fmaxf(h1 + sb1[lane], 0.f);
            contrib = h1 * sWa[lane];
        }
        #pragma unroll
        for (int off = 32; off > 0; off >>= 1)
            contrib += __shfl_down(contrib, off);

        if (lane == 0) {
            float logit = contrib + sba;
            out[b] = 1.0f / (1.0f + expf(-logit));
        }
    }
}

// ---------------------------------------------------------------------------
extern "C" void kernel_launch(void* const* d_in, const int* in_sizes, int n_in,
                              void* d_out, int out_size, void* d_ws, size_t ws_size,
                              hipStream_t stream) {
    const int*   users = (const int*)  d_in[0];
    const int*   items = (const int*)  d_in[1];
    const int*   rows  = (const int*)  d_in[2];
    const int*   cols  = (const int*)  d_in[3];
    const float* vals  = (const float*)d_in[4];
    const float* ue    = (const float*)d_in[5];
    const float* ie    = (const float*)d_in[6];
    const float* W0    = (const float*)d_in[7];
    const float* b0    = (const float*)d_in[8];
    const float* W1    = (const float*)d_in[9];
    const float* b1    = (const float*)d_in[10];
    const float* Wa    = (const float*)d_in[11];
    const float* ba    = (const float*)d_in[12];
    float* out = (float*)d_out;

    const size_t nodeElems = (size_t)N_NODES * LATENT;   // 9.6 M
    char* ws = (char*)d_ws;
    unsigned short* tabA = (unsigned short*)ws;  ws += nodeElems * 2;            // 19.2 MB
    unsigned short* tabB = (unsigned short*)ws;  ws += nodeElems * 2;            // 19.2 MB
    float* vsel = (float*)ws;                    ws += (size_t)BATCH * 128 * 4;  // 8.39 MB
    int2*  edges  = (int2*)ws;                   ws += (size_t)N_EDGES * 8;      // 19.2 MB
    int2*  staged = (int2*)ws;                   ws += (size_t)N_EDGES * 8;      // 19.2 MB
    int* counts   = (int*)ws;                    ws += N_NODES * 4;
    int* startArr = (int*)ws;                    ws += N_NODES * 4;
    int* cmat     = (int*)ws;                    ws += (size_t)NBKT * NBLK * 4;  // 686 KB
    int* bsum     = (int*)ws;                    ws += SCAN_GRID * 4;

    const int gGrid = (BATCH * 64) / 256;

    // bf16 table + fp32 layer-0 selection
    k_concat_bf16<<<(N_NODES * (LATENT / 4) + 255) / 256, 256, 0, stream>>>(
        (const float4*)ue, (const float4*)ie, (ushort4*)tabA);
    k_sel_init<<<gGrid, 256, 0, stream>>>(users, items, ue, ie, vsel);

    // ---- CSR build: hist + scan + zero-atomic multisplit fill ----
    hipMemsetAsync(counts, 0, N_NODES * 4, stream);
    k_hist<<<(N_EDGES + 255) / 256, 256, 0, stream>>>(rows, counts);
    k_scan_a<<<SCAN_GRID, SCAN_BLK, 0, stream>>>(counts, startArr, bsum);
    k_scan_b<<<1, 256, 0, stream>>>(bsum, SCAN_GRID);
    k_scan_c<<<SCAN_GRID, SCAN_BLK, 0, stream>>>(startArr, bsum);
    k_p1a<<<NBLK, 256, 0, stream>>>(rows, cmat);
    k_p1b<<<NBKT, 1024, 0, stream>>>(startArr, cmat);
    k_p1c<<<NBLK, 256, 0, stream>>>(rows, cols, vals, cmat, staged);
    k_p2<<<NBKT, 256, 0, stream>>>(startArr, staged, edges);

    // layer 1: A -> B (writes every row; no memset needed)
    k_spmm_csr<<<(N_NODES + 3) / 4, 256, 0, stream>>>(startArr, counts, edges, tabA, tabB);
    k_gather_add<<<gGrid, 256, 0, stream>>>(users, items, tabB, vsel);

    // layer 2: B -> A
    k_spmm_csr<<<(N_NODES + 3) / 4, 256, 0, stream>>>(startArr, counts, edges, tabB, tabA);

    // layer 3 (selected rows only) fused with layer-2 gather_add
    k_spmm_sel<<<(2 * BATCH) / 4, 256, 0, stream>>>(users, items, startArr,
                                                    counts, edges, tabA, vsel);

    // MLP head
    k_mlp<<<1024, 256, 0, stream>>>(vsel, W0, b0, W1, b1, Wa, ba, out);
}

// Round 8
// 418.351 us; speedup vs baseline: 3.5597x; 1.2076x over previous
//
#include <hip/hip_runtime.h>
#include <math.h>

#define NUM_USERS 100000
#define NUM_ITEMS 50000
#define N_NODES   150000   // NUM_USERS + NUM_ITEMS
#define LATENT    64
#define N_EDGES   2400000
#define BATCH     16384

// Multisplit fill: 4096-edge chunks, 512-row buckets
#define CHUNK 4096
#define NBLK  ((N_EDGES + CHUNK - 1) / CHUNK)   // 586
#define NBKT  ((N_NODES + 511) / 512)           // 293

// bf16 helpers (values small/finite; RNE)
__device__ __forceinline__ unsigned short f2bf(float f) {
    unsigned u = __float_as_uint(f);
    u = (u + 0x7FFF + ((u >> 16) & 1)) >> 16;
    return (unsigned short)u;
}
__device__ __forceinline__ float bf2f(unsigned short h) {
    return __uint_as_float(((unsigned)h) << 16);
}

// ---------------------------------------------------------------------------
// table = bf16(concat(user_emb, item_emb))
// ---------------------------------------------------------------------------
__global__ void k_concat_bf16(const float4* __restrict__ ue,
                              const float4* __restrict__ ie,
                              ushort4* __restrict__ cur) {
    int i = blockIdx.x * blockDim.x + threadIdx.x;
    const int nU4 = NUM_USERS * (LATENT / 4);
    const int nT4 = N_NODES   * (LATENT / 4);
    if (i >= nT4) return;
    float4 v = (i < nU4) ? ue[i] : ie[i - nU4];
    ushort4 o;
    o.x = f2bf(v.x); o.y = f2bf(v.y); o.z = f2bf(v.z); o.w = f2bf(v.w);
    cur[i] = o;
}

// ---------------------------------------------------------------------------
// vsel[b, 0:64] = user_emb[users[b]] ; vsel[b,64:128] = item_emb[items[b]]
// ---------------------------------------------------------------------------
__global__ void k_sel_init(const int* __restrict__ users,
                           const int* __restrict__ items,
                           const float* __restrict__ ue,
                           const float* __restrict__ ie,
                           float* __restrict__ vsel) {
    int t = blockIdx.x * blockDim.x + threadIdx.x;
    int b = t >> 6, d = t & 63;
    vsel[b * 128 + d]      = ue[users[b] * 64 + d];
    vsel[b * 128 + 64 + d] = ie[items[b] * 64 + d];
}

// ---------------------------------------------------------------------------
// Multisplit p1a: per-block bucket histogram -> cmat[bucket][block]
// (LDS atomics only; no global atomics anywhere in the build)
// ---------------------------------------------------------------------------
__global__ __launch_bounds__(256) void k_p1a(const int* __restrict__ rows,
                                             int* __restrict__ cmat) {
    __shared__ int hist[NBKT];
    for (int i = threadIdx.x; i < NBKT; i += 256) hist[i] = 0;
    __syncthreads();
    int e0 = blockIdx.x * CHUNK;
    int cnt = min(CHUNK, N_EDGES - e0);
    for (int t = threadIdx.x; t < cnt; t += 256)
        atomicAdd(&hist[rows[e0 + t] >> 9], 1);
    __syncthreads();
    for (int i = threadIdx.x; i < NBKT; i += 256)
        cmat[i * NBLK + blockIdx.x] = hist[i];
}

// ---------------------------------------------------------------------------
// Multisplit p1b: per-bucket exclusive scan over blocks (no base yet);
// emit bucket total.
// ---------------------------------------------------------------------------
__global__ __launch_bounds__(1024) void k_p1b(int* __restrict__ cmat,
                                              int* __restrict__ btotal) {
    __shared__ int sh[1024];
    int k = blockIdx.x;
    int v = (threadIdx.x < NBLK) ? cmat[k * NBLK + threadIdx.x] : 0;
    sh[threadIdx.x] = v;
    __syncthreads();
    for (int off = 1; off < 1024; off <<= 1) {
        int t = (threadIdx.x >= off) ? sh[threadIdx.x - off] : 0;
        __syncthreads();
        sh[threadIdx.x] += t;
        __syncthreads();
    }
    if (threadIdx.x < NBLK)
        cmat[k * NBLK + threadIdx.x] = sh[threadIdx.x] - v;   // exclusive
    if (threadIdx.x == 1023) btotal[k] = sh[1023];
}

// ---------------------------------------------------------------------------
// Bucket-base scan: exclusive scan of 293 bucket totals -> bbase[0..NBKT]
// ---------------------------------------------------------------------------
__global__ __launch_bounds__(512) void k_bscan(const int* __restrict__ btotal,
                                               int* __restrict__ bbase) {
    __shared__ int sh[512];
    int v = (threadIdx.x < NBKT) ? btotal[threadIdx.x] : 0;
    sh[threadIdx.x] = v;
    __syncthreads();
    for (int off = 1; off < 512; off <<= 1) {
        int t = (threadIdx.x >= off) ? sh[threadIdx.x - off] : 0;
        __syncthreads();
        sh[threadIdx.x] += t;
        __syncthreads();
    }
    if (threadIdx.x < NBKT) bbase[threadIdx.x] = sh[threadIdx.x] - v;
    if (threadIdx.x == NBKT) bbase[NBKT] = N_EDGES;
    if (NBKT >= 512 && threadIdx.x == 0) bbase[NBKT] = N_EDGES; // safety (unused)
}

// ---------------------------------------------------------------------------
// Multisplit p1c: re-read chunk, bin records in LDS, flush bucket-contiguous
// runs at exact offsets (cmat + bbase). Zero global atomics.
// Record: x = col(18b) | rowLo(9b)<<18 ; y = fp32 val bits.
// ---------------------------------------------------------------------------
__global__ __launch_bounds__(256) void k_p1c(const int* __restrict__ rows,
                                             const int* __restrict__ cols,
                                             const float* __restrict__ vals,
                                             const int* __restrict__ offs,
                                             const int* __restrict__ bbase,
                                             int2* __restrict__ staged) {
    __shared__ int hist[NBKT];
    __shared__ int lstart[NBKT];
    __shared__ int cursor[NBKT];
    __shared__ int soffs[NBKT];
    __shared__ int sc[512];
    __shared__ int2 st[CHUNK];
    __shared__ unsigned short bkt16[CHUNK];

    int e0 = blockIdx.x * CHUNK;
    int cnt = min(CHUNK, N_EDGES - e0);
    for (int i = threadIdx.x; i < NBKT; i += 256) {
        hist[i] = 0; cursor[i] = 0;
        soffs[i] = offs[i * NBLK + blockIdx.x] + bbase[i];
    }
    sc[threadIdx.x] = 0; sc[threadIdx.x + 256] = 0;
    __syncthreads();
    for (int t = threadIdx.x; t < cnt; t += 256)
        atomicAdd(&hist[rows[e0 + t] >> 9], 1);
    __syncthreads();
    for (int i = threadIdx.x; i < NBKT; i += 256) sc[i] = hist[i];
    __syncthreads();
    // inclusive scan over 512 slots (256 threads x 2, Hillis-Steele)
    for (int off = 1; off < 512; off <<= 1) {
        int a0 = (threadIdx.x >= off)       ? sc[threadIdx.x - off]       : 0;
        int a1 = (threadIdx.x + 256 >= off) ? sc[threadIdx.x + 256 - off] : 0;
        __syncthreads();
        sc[threadIdx.x]       += a0;
        sc[threadIdx.x + 256] += a1;
        __syncthreads();
    }
    for (int i = threadIdx.x; i < NBKT; i += 256) lstart[i] = sc[i] - hist[i];
    __syncthreads();
    // bin into LDS staging
    for (int t = threadIdx.x; t < cnt; t += 256) {
        int r = rows[e0 + t];
        int b = r >> 9;
        int p = lstart[b] + atomicAdd(&cursor[b], 1);
        st[p] = make_int2(cols[e0 + t] | ((r & 511) << 18),
                          __float_as_int(vals[e0 + t]));
        bkt16[p] = (unsigned short)b;
    }
    __syncthreads();
    // flush: consecutive threads in a bucket write consecutive global addrs
    for (int t = threadIdx.x; t < cnt; t += 256) {
        int b = bkt16[t];
        staged[soffs[b] + (t - lstart[b])] = st[t];
    }
}

// ---------------------------------------------------------------------------
// Multisplit p2: one block per bucket. Pass 1 builds the 512-row histogram
// from staged records (this REPLACES the global k_hist + row scan); LDS scan
// gives local row starts; pass 2 places records row-contiguously. Finally
// writes counts[] and startArr[] for the SpMM.
// ---------------------------------------------------------------------------
__global__ __launch_bounds__(256) void k_p2(const int* __restrict__ bbase,
                                            const int2* __restrict__ staged,
                                            int2* __restrict__ edges,
                                            int* __restrict__ counts,
                                            int* __restrict__ startArr) {
    __shared__ int hist[512];
    __shared__ int lstart[512];
    __shared__ int cur[512];
    __shared__ int sc[512];
    int k = blockIdx.x;
    int rowBase = k << 9;
    int numRows = min(512, N_NODES - rowBase);
    int base = bbase[k];
    int end  = bbase[k + 1];
    hist[threadIdx.x] = 0;       hist[threadIdx.x + 256] = 0;
    cur[threadIdx.x] = 0;        cur[threadIdx.x + 256] = 0;
    __syncthreads();
    int cnt = end - base;
    // pass 1: row histogram from staged records
    for (int t = threadIdx.x; t < cnt; t += 256)
        atomicAdd(&hist[((unsigned)staged[base + t].x) >> 18], 1);
    __syncthreads();
    sc[threadIdx.x] = hist[threadIdx.x];
    sc[threadIdx.x + 256] = hist[threadIdx.x + 256];
    __syncthreads();
    for (int off = 1; off < 512; off <<= 1) {
        int a0 = (threadIdx.x >= off)       ? sc[threadIdx.x - off]       : 0;
        int a1 = (threadIdx.x + 256 >= off) ? sc[threadIdx.x + 256 - off] : 0;
        __syncthreads();
        sc[threadIdx.x]       += a0;
        sc[threadIdx.x + 256] += a1;
        __syncthreads();
    }
    lstart[threadIdx.x]       = sc[threadIdx.x]       - hist[threadIdx.x];
    lstart[threadIdx.x + 256] = sc[threadIdx.x + 256] - hist[threadIdx.x + 256];
    __syncthreads();
    // pass 2: place records row-contiguously within the bucket window
    for (int t = threadIdx.x; t < cnt; t += 256) {
        int2 rec = staged[base + t];
        int rl = ((unsigned)rec.x) >> 18;
        int c  = rec.x & 0x3FFFF;
        int off = lstart[rl] + atomicAdd(&cur[rl], 1);
        edges[base + off] = make_int2(c, rec.y);
    }
    // emit row-level CSR metadata
    for (int i = threadIdx.x; i < numRows; i += 256) {
        counts[rowBase + i]   = hist[i];
        startArr[rowBase + i] = base + lstart[i];
    }
}

// ---------------------------------------------------------------------------
// Gather SpMM (bf16): one wave per row, lane = dim, unroll 8.
// ---------------------------------------------------------------------------
__global__ __launch_bounds__(256) void k_spmm_csr(const int* __restrict__ startArr,
                                                  const int* __restrict__ counts,
                                                  const int2* __restrict__ edges,
                                                  const unsigned short* __restrict__ cur,
                                                  unsigned short* __restrict__ nxt) {
    int row  = blockIdx.x * 4 + (threadIdx.x >> 6);
    int lane = threadIdx.x & 63;
    if (row >= N_NODES) return;
    row = __builtin_amdgcn_readfirstlane(row);
    int s = __builtin_amdgcn_readfirstlane(startArr[row]);
    int n = __builtin_amdgcn_readfirstlane(counts[row]);
    float acc = 0.f;
    int j = 0;
    for (; j + 8 <= n; j += 8) {
        int2 e0 = edges[s + j + 0];
        int2 e1 = edges[s + j + 1];
        int2 e2 = edges[s + j + 2];
        int2 e3 = edges[s + j + 3];
        int2 e4 = edges[s + j + 4];
        int2 e5 = edges[s + j + 5];
        int2 e6 = edges[s + j + 6];
        int2 e7 = edges[s + j + 7];
        float x0 = bf2f(cur[(size_t)e0.x * 64 + lane]);
        float x1 = bf2f(cur[(size_t)e1.x * 64 + lane]);
        float x2 = bf2f(cur[(size_t)e2.x * 64 + lane]);
        float x3 = bf2f(cur[(size_t)e3.x * 64 + lane]);
        float x4 = bf2f(cur[(size_t)e4.x * 64 + lane]);
        float x5 = bf2f(cur[(size_t)e5.x * 64 + lane]);
        float x6 = bf2f(cur[(size_t)e6.x * 64 + lane]);
        float x7 = bf2f(cur[(size_t)e7.x * 64 + lane]);
        acc = fmaf(__int_as_float(e0.y), x0, acc);
        acc = fmaf(__int_as_float(e1.y), x1, acc);
        acc = fmaf(__int_as_float(e2.y), x2, acc);
        acc = fmaf(__int_as_float(e3.y), x3, acc);
        acc = fmaf(__int_as_float(e4.y), x4, acc);
        acc = fmaf(__int_as_float(e5.y), x5, acc);
        acc = fmaf(__int_as_float(e6.y), x6, acc);
        acc = fmaf(__int_as_float(e7.y), x7, acc);
    }
    for (; j + 4 <= n; j += 4) {
        int2 e0 = edges[s + j + 0];
        int2 e1 = edges[s + j + 1];
        int2 e2 = edges[s + j + 2];
        int2 e3 = edges[s + j + 3];
        float x0 = bf2f(cur[(size_t)e0.x * 64 + lane]);
        float x1 = bf2f(cur[(size_t)e1.x * 64 + lane]);
        float x2 = bf2f(cur[(size_t)e2.x * 64 + lane]);
        float x3 = bf2f(cur[(size_t)e3.x * 64 + lane]);
        acc = fmaf(__int_as_float(e0.y), x0, acc);
        acc = fmaf(__int_as_float(e1.y), x1, acc);
        acc = fmaf(__int_as_float(e2.y), x2, acc);
        acc = fmaf(__int_as_float(e3.y), x3, acc);
    }
    for (; j < n; j++) {
        int2 e = edges[s + j];
        acc = fmaf(__int_as_float(e.y), bf2f(cur[(size_t)e.x * 64 + lane]), acc);
    }
    nxt[(size_t)row * 64 + lane] = f2bf(acc);
}

// ---------------------------------------------------------------------------
// Fused layer-3 + layer-2 gather_add at selected rows.
// ---------------------------------------------------------------------------
__global__ __launch_bounds__(256) void k_spmm_sel(const int* __restrict__ users,
                                                  const int* __restrict__ items,
                                                  const int* __restrict__ startArr,
                                                  const int* __restrict__ counts,
                                                  const int2* __restrict__ edges,
                                                  const unsigned short* __restrict__ cur,
                                                  float* __restrict__ vsel) {
    int wave = blockIdx.x * 4 + (threadIdx.x >> 6);
    int lane = threadIdx.x & 63;
    int b, row;
    float* dst;
    if (wave < BATCH) {
        b = wave; row = users[b];
        dst = &vsel[b * 128 + lane];
    } else {
        b = wave - BATCH; row = NUM_USERS + items[b];
        dst = &vsel[b * 128 + 64 + lane];
    }
    int s = startArr[row];
    int n = counts[row];
    float acc = bf2f(cur[(size_t)row * 64 + lane]);   // layer-2 contribution
    int j = 0;
    for (; j + 8 <= n; j += 8) {
        int2 e0 = edges[s + j + 0];
        int2 e1 = edges[s + j + 1];
        int2 e2 = edges[s + j + 2];
        int2 e3 = edges[s + j + 3];
        int2 e4 = edges[s + j + 4];
        int2 e5 = edges[s + j + 5];
        int2 e6 = edges[s + j + 6];
        int2 e7 = edges[s + j + 7];
        float x0 = bf2f(cur[(size_t)e0.x * 64 + lane]);
        float x1 = bf2f(cur[(size_t)e1.x * 64 + lane]);
        float x2 = bf2f(cur[(size_t)e2.x * 64 + lane]);
        float x3 = bf2f(cur[(size_t)e3.x * 64 + lane]);
        float x4 = bf2f(cur[(size_t)e4.x * 64 + lane]);
        float x5 = bf2f(cur[(size_t)e5.x * 64 + lane]);
        float x6 = bf2f(cur[(size_t)e6.x * 64 + lane]);
        float x7 = bf2f(cur[(size_t)e7.x * 64 + lane]);
        acc = fmaf(__int_as_float(e0.y), x0, acc);
        acc = fmaf(__int_as_float(e1.y), x1, acc);
        acc = fmaf(__int_as_float(e2.y), x2, acc);
        acc = fmaf(__int_as_float(e3.y), x3, acc);
        acc = fmaf(__int_as_float(e4.y), x4, acc);
        acc = fmaf(__int_as_float(e5.y), x5, acc);
        acc = fmaf(__int_as_float(e6.y), x6, acc);
        acc = fmaf(__int_as_float(e7.y), x7, acc);
    }
    for (; j + 4 <= n; j += 4) {
        int2 e0 = edges[s + j + 0];
        int2 e1 = edges[s + j + 1];
        int2 e2 = edges[s + j + 2];
        int2 e3 = edges[s + j + 3];
        float x0 = bf2f(cur[(size_t)e0.x * 64 + lane]);
        float x1 = bf2f(cur[(size_t)e1.x * 64 + lane]);
        float x2 = bf2f(cur[(size_t)e2.x * 64 + lane]);
        float x3 = bf2f(cur[(size_t)e3.x * 64 + lane]);
        acc = fmaf(__int_as_float(e0.y), x0, acc);
        acc = fmaf(__int_as_float(e1.y), x1, acc);
        acc = fmaf(__int_as_float(e2.y), x2, acc);
        acc = fmaf(__int_as_float(e3.y), x3, acc);
    }
    for (; j < n; j++) {
        int2 e = edges[s + j];
        acc = fmaf(__int_as_float(e.y), bf2f(cur[(size_t)e.x * 64 + lane]), acc);
    }
    *dst += acc;
}

// ---------------------------------------------------------------------------
// vsel += bf16 src at selected rows (after layer 1)
// ---------------------------------------------------------------------------
__global__ void k_gather_add(const int* __restrict__ users,
                             const int* __restrict__ items,
                             const unsigned short* __restrict__ src,
                             float* __restrict__ vsel) {
    int t = blockIdx.x * blockDim.x + threadIdx.x;
    int b = t >> 6, d = t & 63;
    vsel[b * 128 + d]      += bf2f(src[(size_t)users[b] * 64 + d]);
    vsel[b * 128 + 64 + d] += bf2f(src[(size_t)(NUM_USERS + items[b]) * 64 + d]);
}

// ---------------------------------------------------------------------------
// MLP head: one wave per batch row, weights in LDS.
// ---------------------------------------------------------------------------
__global__ __launch_bounds__(256) void k_mlp(const float* __restrict__ vsel,
                                             const float* __restrict__ W0,
                                             const float* __restrict__ b0,
                                             const float* __restrict__ W1,
                                             const float* __restrict__ b1,
                                             const float* __restrict__ Wa,
                                             const float* __restrict__ ba,
                                             float* __restrict__ out) {
    __shared__ float sW0[128 * 64];
    __shared__ float sW1[64 * 32];
    __shared__ float sWa[32];
    __shared__ float sb0[64];
    __shared__ float sb1[32];

    for (int i = threadIdx.x; i < 128 * 64; i += 256) sW0[i] = W0[i];
    for (int i = threadIdx.x; i < 64 * 32;  i += 256) sW1[i] = W1[i];
    if (threadIdx.x < 32) sWa[threadIdx.x] = Wa[threadIdx.x];
    if (threadIdx.x < 64) sb0[threadIdx.x] = b0[threadIdx.x];
    if (threadIdx.x >= 64 && threadIdx.x < 96) sb1[threadIdx.x - 64] = b1[threadIdx.x - 64];
    float sba = ba[0];
    __syncthreads();

    int lane   = threadIdx.x & 63;
    int wave   = blockIdx.x * (blockDim.x >> 6) + (threadIdx.x >> 6);
    int nwaves = gridDim.x * (blockDim.x >> 6);

    for (int b = wave; b < BATCH; b += nwaves) {
        float vlo = vsel[b * 128 + lane]      * 0.25f;
        float vhi = vsel[b * 128 + 64 + lane] * 0.25f;

        float h0 = 0.f;
        #pragma unroll
        for (int k = 0; k < 64; k++) {
            float a = __shfl(vlo, k);
            h0 = fmaf(a, sW0[k * 64 + lane], h0);
        }
        #pragma unroll
        for (int k = 0; k < 64; k++) {
            float a = __shfl(vhi, k);
            h0 = fmaf(a, sW0[(64 + k) * 64 + lane], h0);
        }
        h0 = fmaxf(h0 + sb0[lane], 0.f);

        float h1 = 0.f;
        #pragma unroll
        for (int k = 0; k < 64; k++) {
            float a = __shfl(h0, k);
            if (lane < 32) h1 = fmaf(a, sW1[k * 32 + lane], h1);
        }
        float contrib = 0.f;
        if (lane < 32) {
            h1 = fmaxf(h1 + sb1[lane], 0.f);
            contrib = h1 * sWa[lane];
        }
        #pragma unroll
        for (int off = 32; off > 0; off >>= 1)
            contrib += __shfl_down(contrib, off);

        if (lane == 0) {
            float logit = contrib + sba;
            out[b] = 1.0f / (1.0f + expf(-logit));
        }
    }
}

// ---------------------------------------------------------------------------
extern "C" void kernel_launch(void* const* d_in, const int* in_sizes, int n_in,
                              void* d_out, int out_size, void* d_ws, size_t ws_size,
                              hipStream_t stream) {
    const int*   users = (const int*)  d_in[0];
    const int*   items = (const int*)  d_in[1];
    const int*   rows  = (const int*)  d_in[2];
    const int*   cols  = (const int*)  d_in[3];
    const float* vals  = (const float*)d_in[4];
    const float* ue    = (const float*)d_in[5];
    const float* ie    = (const float*)d_in[6];
    const float* W0    = (const float*)d_in[7];
    const float* b0    = (const float*)d_in[8];
    const float* W1    = (const float*)d_in[9];
    const float* b1    = (const float*)d_in[10];
    const float* Wa    = (const float*)d_in[11];
    const float* ba    = (const float*)d_in[12];
    float* out = (float*)d_out;

    const size_t nodeElems = (size_t)N_NODES * LATENT;   // 9.6 M
    char* ws = (char*)d_ws;
    unsigned short* tabA = (unsigned short*)ws;  ws += nodeElems * 2;            // 19.2 MB
    unsigned short* tabB = (unsigned short*)ws;  ws += nodeElems * 2;            // 19.2 MB
    float* vsel = (float*)ws;                    ws += (size_t)BATCH * 128 * 4;  // 8.39 MB
    int2*  edges  = (int2*)ws;                   ws += (size_t)N_EDGES * 8;      // 19.2 MB
    int2*  staged = (int2*)ws;                   ws += (size_t)N_EDGES * 8;      // 19.2 MB
    int* counts   = (int*)ws;                    ws += N_NODES * 4;
    int* startArr = (int*)ws;                    ws += N_NODES * 4;
    int* cmat     = (int*)ws;                    ws += (size_t)NBKT * NBLK * 4;  // 686 KB
    int* btotal   = (int*)ws;                    ws += NBKT * 4;
    int* bbase    = (int*)ws;                    ws += (NBKT + 1) * 4;

    const int gGrid = (BATCH * 64) / 256;

    // bf16 table + fp32 layer-0 selection
    k_concat_bf16<<<(N_NODES * (LATENT / 4) + 255) / 256, 256, 0, stream>>>(
        (const float4*)ue, (const float4*)ie, (ushort4*)tabA);
    k_sel_init<<<gGrid, 256, 0, stream>>>(users, items, ue, ie, vsel);

    // ---- CSR build: zero global atomics, no row histogram ----
    k_p1a<<<NBLK, 256, 0, stream>>>(rows, cmat);
    k_p1b<<<NBKT, 1024, 0, stream>>>(cmat, btotal);
    k_bscan<<<1, 512, 0, stream>>>(btotal, bbase);
    k_p1c<<<NBLK, 256, 0, stream>>>(rows, cols, vals, cmat, bbase, staged);
    k_p2<<<NBKT, 256, 0, stream>>>(bbase, staged, edges, counts, startArr);

    // layer 1: A -> B (writes every row; no memset needed)
    k_spmm_csr<<<(N_NODES + 3) / 4, 256, 0, stream>>>(startArr, counts, edges, tabA, tabB);
    k_gather_add<<<gGrid, 256, 0, stream>>>(users, items, tabB, vsel);

    // layer 2: B -> A
    k_spmm_csr<<<(N_NODES + 3) / 4, 256, 0, stream>>>(startArr, counts, edges, tabB, tabA);

    // layer 3 (selected rows only) fused with layer-2 gather_add
    k_spmm_sel<<<(2 * BATCH) / 4, 256, 0, stream>>>(users, items, startArr,
                                                    counts, edges, tabA, vsel);

    // MLP head
    k_mlp<<<1024, 256, 0, stream>>>(vsel, W0, b0, W1, b1, Wa, ba, out);
}

// Round 9
// 385.515 us; speedup vs baseline: 3.8629x; 1.0852x over previous
//
#include <hip/hip_runtime.h>
#include <math.h>

#define NUM_USERS 100000
#define NUM_ITEMS 50000
#define N_NODES   150000   // NUM_USERS + NUM_ITEMS
#define LATENT    64
#define N_EDGES   2400000
#define BATCH     16384

// Multisplit fill: 4096-edge chunks, 512-row buckets
#define CHUNK 4096
#define NBLK  ((N_EDGES + CHUNK - 1) / CHUNK)   // 586
#define NBKT  ((N_NODES + 511) / 512)           // 293

// bf16 helpers (values small/finite; RNE)
__device__ __forceinline__ unsigned short f2bf(float f) {
    unsigned u = __float_as_uint(f);
    u = (u + 0x7FFF + ((u >> 16) & 1)) >> 16;
    return (unsigned short)u;
}
__device__ __forceinline__ float bf2f(unsigned short h) {
    return __uint_as_float(((unsigned)h) << 16);
}

// ---------------------------------------------------------------------------
// table = bf16(concat(user_emb, item_emb))
// ---------------------------------------------------------------------------
__global__ void k_concat_bf16(const float4* __restrict__ ue,
                              const float4* __restrict__ ie,
                              ushort4* __restrict__ cur) {
    int i = blockIdx.x * blockDim.x + threadIdx.x;
    const int nU4 = NUM_USERS * (LATENT / 4);
    const int nT4 = N_NODES   * (LATENT / 4);
    if (i >= nT4) return;
    float4 v = (i < nU4) ? ue[i] : ie[i - nU4];
    ushort4 o;
    o.x = f2bf(v.x); o.y = f2bf(v.y); o.z = f2bf(v.z); o.w = f2bf(v.w);
    cur[i] = o;
}

// ---------------------------------------------------------------------------
// vsel[b, 0:64] = user_emb[users[b]] ; vsel[b,64:128] = item_emb[items[b]]
// ---------------------------------------------------------------------------
__global__ void k_sel_init(const int* __restrict__ users,
                           const int* __restrict__ items,
                           const float* __restrict__ ue,
                           const float* __restrict__ ie,
                           float* __restrict__ vsel) {
    int t = blockIdx.x * blockDim.x + threadIdx.x;
    int b = t >> 6, d = t & 63;
    vsel[b * 128 + d]      = ue[users[b] * 64 + d];
    vsel[b * 128 + 64 + d] = ie[items[b] * 64 + d];
}

// ---------------------------------------------------------------------------
// Multisplit p1a: per-block bucket histogram -> cmat[bucket][block]
// ---------------------------------------------------------------------------
__global__ __launch_bounds__(256) void k_p1a(const int* __restrict__ rows,
                                             int* __restrict__ cmat) {
    __shared__ int hist[NBKT];
    for (int i = threadIdx.x; i < NBKT; i += 256) hist[i] = 0;
    __syncthreads();
    int e0 = blockIdx.x * CHUNK;
    int cnt = min(CHUNK, N_EDGES - e0);
    for (int t = threadIdx.x; t < cnt; t += 256)
        atomicAdd(&hist[rows[e0 + t] >> 9], 1);
    __syncthreads();
    for (int i = threadIdx.x; i < NBKT; i += 256)
        cmat[i * NBLK + blockIdx.x] = hist[i];
}

// ---------------------------------------------------------------------------
// Multisplit p1b: per-bucket exclusive scan over blocks; emit bucket total.
// ---------------------------------------------------------------------------
__global__ __launch_bounds__(1024) void k_p1b(int* __restrict__ cmat,
                                              int* __restrict__ btotal) {
    __shared__ int sh[1024];
    int k = blockIdx.x;
    int v = (threadIdx.x < NBLK) ? cmat[k * NBLK + threadIdx.x] : 0;
    sh[threadIdx.x] = v;
    __syncthreads();
    for (int off = 1; off < 1024; off <<= 1) {
        int t = (threadIdx.x >= off) ? sh[threadIdx.x - off] : 0;
        __syncthreads();
        sh[threadIdx.x] += t;
        __syncthreads();
    }
    if (threadIdx.x < NBLK)
        cmat[k * NBLK + threadIdx.x] = sh[threadIdx.x] - v;   // exclusive
    if (threadIdx.x == 1023) btotal[k] = sh[1023];
}

// ---------------------------------------------------------------------------
// Bucket-base scan: exclusive scan of 293 bucket totals -> bbase[0..NBKT]
// ---------------------------------------------------------------------------
__global__ __launch_bounds__(512) void k_bscan(const int* __restrict__ btotal,
                                               int* __restrict__ bbase) {
    __shared__ int sh[512];
    int v = (threadIdx.x < NBKT) ? btotal[threadIdx.x] : 0;
    sh[threadIdx.x] = v;
    __syncthreads();
    for (int off = 1; off < 512; off <<= 1) {
        int t = (threadIdx.x >= off) ? sh[threadIdx.x - off] : 0;
        __syncthreads();
        sh[threadIdx.x] += t;
        __syncthreads();
    }
    if (threadIdx.x < NBKT) bbase[threadIdx.x] = sh[threadIdx.x] - v;
    if (threadIdx.x == NBKT) bbase[NBKT] = N_EDGES;
}

// ---------------------------------------------------------------------------
// Multisplit p1c: re-read chunk, bin records in LDS, flush bucket-contiguous
// runs at exact offsets (cmat + bbase). Zero global atomics.
// Record: x = col(18b) | rowLo(9b)<<18 ; y = fp32 val bits.
// ---------------------------------------------------------------------------
__global__ __launch_bounds__(256) void k_p1c(const int* __restrict__ rows,
                                             const int* __restrict__ cols,
                                             const float* __restrict__ vals,
                                             const int* __restrict__ offs,
                                             const int* __restrict__ bbase,
                                             int2* __restrict__ staged) {
    __shared__ int hist[NBKT];
    __shared__ int lstart[NBKT];
    __shared__ int cursor[NBKT];
    __shared__ int soffs[NBKT];
    __shared__ int sc[512];
    __shared__ int2 st[CHUNK];
    __shared__ unsigned short bkt16[CHUNK];

    int e0 = blockIdx.x * CHUNK;
    int cnt = min(CHUNK, N_EDGES - e0);
    for (int i = threadIdx.x; i < NBKT; i += 256) {
        hist[i] = 0; cursor[i] = 0;
        soffs[i] = offs[i * NBLK + blockIdx.x] + bbase[i];
    }
    sc[threadIdx.x] = 0; sc[threadIdx.x + 256] = 0;
    __syncthreads();
    for (int t = threadIdx.x; t < cnt; t += 256)
        atomicAdd(&hist[rows[e0 + t] >> 9], 1);
    __syncthreads();
    for (int i = threadIdx.x; i < NBKT; i += 256) sc[i] = hist[i];
    __syncthreads();
    // inclusive scan over 512 slots (256 threads x 2, Hillis-Steele)
    for (int off = 1; off < 512; off <<= 1) {
        int a0 = (threadIdx.x >= off)       ? sc[threadIdx.x - off]       : 0;
        int a1 = (threadIdx.x + 256 >= off) ? sc[threadIdx.x + 256 - off] : 0;
        __syncthreads();
        sc[threadIdx.x]       += a0;
        sc[threadIdx.x + 256] += a1;
        __syncthreads();
    }
    for (int i = threadIdx.x; i < NBKT; i += 256) lstart[i] = sc[i] - hist[i];
    __syncthreads();
    // bin into LDS staging
    for (int t = threadIdx.x; t < cnt; t += 256) {
        int r = rows[e0 + t];
        int b = r >> 9;
        int p = lstart[b] + atomicAdd(&cursor[b], 1);
        st[p] = make_int2(cols[e0 + t] | ((r & 511) << 18),
                          __float_as_int(vals[e0 + t]));
        bkt16[p] = (unsigned short)b;
    }
    __syncthreads();
    // flush: consecutive threads in a bucket write consecutive global addrs
    for (int t = threadIdx.x; t < cnt; t += 256) {
        int b = bkt16[t];
        staged[soffs[b] + (t - lstart[b])] = st[t];
    }
}

// ---------------------------------------------------------------------------
// Multisplit p2: one block per bucket; row histogram from staged records,
// LDS scan -> local row starts, place records, emit counts/startArr.
// ---------------------------------------------------------------------------
__global__ __launch_bounds__(256) void k_p2(const int* __restrict__ bbase,
                                            const int2* __restrict__ staged,
                                            int2* __restrict__ edges,
                                            int* __restrict__ counts,
                                            int* __restrict__ startArr) {
    __shared__ int hist[512];
    __shared__ int lstart[512];
    __shared__ int cur[512];
    __shared__ int sc[512];
    int k = blockIdx.x;
    int rowBase = k << 9;
    int numRows = min(512, N_NODES - rowBase);
    int base = bbase[k];
    int end  = bbase[k + 1];
    hist[threadIdx.x] = 0;       hist[threadIdx.x + 256] = 0;
    cur[threadIdx.x] = 0;        cur[threadIdx.x + 256] = 0;
    __syncthreads();
    int cnt = end - base;
    for (int t = threadIdx.x; t < cnt; t += 256)
        atomicAdd(&hist[((unsigned)staged[base + t].x) >> 18], 1);
    __syncthreads();
    sc[threadIdx.x] = hist[threadIdx.x];
    sc[threadIdx.x + 256] = hist[threadIdx.x + 256];
    __syncthreads();
    for (int off = 1; off < 512; off <<= 1) {
        int a0 = (threadIdx.x >= off)       ? sc[threadIdx.x - off]       : 0;
        int a1 = (threadIdx.x + 256 >= off) ? sc[threadIdx.x + 256 - off] : 0;
        __syncthreads();
        sc[threadIdx.x]       += a0;
        sc[threadIdx.x + 256] += a1;
        __syncthreads();
    }
    lstart[threadIdx.x]       = sc[threadIdx.x]       - hist[threadIdx.x];
    lstart[threadIdx.x + 256] = sc[threadIdx.x + 256] - hist[threadIdx.x + 256];
    __syncthreads();
    for (int t = threadIdx.x; t < cnt; t += 256) {
        int2 rec = staged[base + t];
        int rl = ((unsigned)rec.x) >> 18;
        int c  = rec.x & 0x3FFFF;
        int off = lstart[rl] + atomicAdd(&cur[rl], 1);
        edges[base + off] = make_int2(c, rec.y);
    }
    for (int i = threadIdx.x; i < numRows; i += 256) {
        counts[rowBase + i]   = hist[i];
        startArr[rowBase + i] = base + lstart[i];
    }
}

// ---------------------------------------------------------------------------
// Gather SpMM (bf16): one wave per row, lane = dim, unroll 8.
// ---------------------------------------------------------------------------
__global__ __launch_bounds__(256) void k_spmm_csr(const int* __restrict__ startArr,
                                                  const int* __restrict__ counts,
                                                  const int2* __restrict__ edges,
                                                  const unsigned short* __restrict__ cur,
                                                  unsigned short* __restrict__ nxt) {
    int row  = blockIdx.x * 4 + (threadIdx.x >> 6);
    int lane = threadIdx.x & 63;
    if (row >= N_NODES) return;
    row = __builtin_amdgcn_readfirstlane(row);
    int s = __builtin_amdgcn_readfirstlane(startArr[row]);
    int n = __builtin_amdgcn_readfirstlane(counts[row]);
    float acc = 0.f;
    int j = 0;
    for (; j + 8 <= n; j += 8) {
        int2 e0 = edges[s + j + 0];
        int2 e1 = edges[s + j + 1];
        int2 e2 = edges[s + j + 2];
        int2 e3 = edges[s + j + 3];
        int2 e4 = edges[s + j + 4];
        int2 e5 = edges[s + j + 5];
        int2 e6 = edges[s + j + 6];
        int2 e7 = edges[s + j + 7];
        float x0 = bf2f(cur[(size_t)e0.x * 64 + lane]);
        float x1 = bf2f(cur[(size_t)e1.x * 64 + lane]);
        float x2 = bf2f(cur[(size_t)e2.x * 64 + lane]);
        float x3 = bf2f(cur[(size_t)e3.x * 64 + lane]);
        float x4 = bf2f(cur[(size_t)e4.x * 64 + lane]);
        float x5 = bf2f(cur[(size_t)e5.x * 64 + lane]);
        float x6 = bf2f(cur[(size_t)e6.x * 64 + lane]);
        float x7 = bf2f(cur[(size_t)e7.x * 64 + lane]);
        acc = fmaf(__int_as_float(e0.y), x0, acc);
        acc = fmaf(__int_as_float(e1.y), x1, acc);
        acc = fmaf(__int_as_float(e2.y), x2, acc);
        acc = fmaf(__int_as_float(e3.y), x3, acc);
        acc = fmaf(__int_as_float(e4.y), x4, acc);
        acc = fmaf(__int_as_float(e5.y), x5, acc);
        acc = fmaf(__int_as_float(e6.y), x6, acc);
        acc = fmaf(__int_as_float(e7.y), x7, acc);
    }
    for (; j + 4 <= n; j += 4) {
        int2 e0 = edges[s + j + 0];
        int2 e1 = edges[s + j + 1];
        int2 e2 = edges[s + j + 2];
        int2 e3 = edges[s + j + 3];
        float x0 = bf2f(cur[(size_t)e0.x * 64 + lane]);
        float x1 = bf2f(cur[(size_t)e1.x * 64 + lane]);
        float x2 = bf2f(cur[(size_t)e2.x * 64 + lane]);
        float x3 = bf2f(cur[(size_t)e3.x * 64 + lane]);
        acc = fmaf(__int_as_float(e0.y), x0, acc);
        acc = fmaf(__int_as_float(e1.y), x1, acc);
        acc = fmaf(__int_as_float(e2.y), x2, acc);
        acc = fmaf(__int_as_float(e3.y), x3, acc);
    }
    for (; j < n; j++) {
        int2 e = edges[s + j];
        acc = fmaf(__int_as_float(e.y), bf2f(cur[(size_t)e.x * 64 + lane]), acc);
    }
    nxt[(size_t)row * 64 + lane] = f2bf(acc);
}

// ---------------------------------------------------------------------------
// Fused layer-3 + layer-2 gather_add at selected rows.
// ---------------------------------------------------------------------------
__global__ __launch_bounds__(256) void k_spmm_sel(const int* __restrict__ users,
                                                  const int* __restrict__ items,
                                                  const int* __restrict__ startArr,
                                                  const int* __restrict__ counts,
                                                  const int2* __restrict__ edges,
                                                  const unsigned short* __restrict__ cur,
                                                  float* __restrict__ vsel) {
    int wave = blockIdx.x * 4 + (threadIdx.x >> 6);
    int lane = threadIdx.x & 63;
    int b, row;
    float* dst;
    if (wave < BATCH) {
        b = wave; row = users[b];
        dst = &vsel[b * 128 + lane];
    } else {
        b = wave - BATCH; row = NUM_USERS + items[b];
        dst = &vsel[b * 128 + 64 + lane];
    }
    int s = startArr[row];
    int n = counts[row];
    float acc = bf2f(cur[(size_t)row * 64 + lane]);   // layer-2 contribution
    int j = 0;
    for (; j + 8 <= n; j += 8) {
        int2 e0 = edges[s + j + 0];
        int2 e1 = edges[s + j + 1];
        int2 e2 = edges[s + j + 2];
        int2 e3 = edges[s + j + 3];
        int2 e4 = edges[s + j + 4];
        int2 e5 = edges[s + j + 5];
        int2 e6 = edges[s + j + 6];
        int2 e7 = edges[s + j + 7];
        float x0 = bf2f(cur[(size_t)e0.x * 64 + lane]);
        float x1 = bf2f(cur[(size_t)e1.x * 64 + lane]);
        float x2 = bf2f(cur[(size_t)e2.x * 64 + lane]);
        float x3 = bf2f(cur[(size_t)e3.x * 64 + lane]);
        float x4 = bf2f(cur[(size_t)e4.x * 64 + lane]);
        float x5 = bf2f(cur[(size_t)e5.x * 64 + lane]);
        float x6 = bf2f(cur[(size_t)e6.x * 64 + lane]);
        float x7 = bf2f(cur[(size_t)e7.x * 64 + lane]);
        acc = fmaf(__int_as_float(e0.y), x0, acc);
        acc = fmaf(__int_as_float(e1.y), x1, acc);
        acc = fmaf(__int_as_float(e2.y), x2, acc);
        acc = fmaf(__int_as_float(e3.y), x3, acc);
        acc = fmaf(__int_as_float(e4.y), x4, acc);
        acc = fmaf(__int_as_float(e5.y), x5, acc);
        acc = fmaf(__int_as_float(e6.y), x6, acc);
        acc = fmaf(__int_as_float(e7.y), x7, acc);
    }
    for (; j + 4 <= n; j += 4) {
        int2 e0 = edges[s + j + 0];
        int2 e1 = edges[s + j + 1];
        int2 e2 = edges[s + j + 2];
        int2 e3 = edges[s + j + 3];
        float x0 = bf2f(cur[(size_t)e0.x * 64 + lane]);
        float x1 = bf2f(cur[(size_t)e1.x * 64 + lane]);
        float x2 = bf2f(cur[(size_t)e2.x * 64 + lane]);
        float x3 = bf2f(cur[(size_t)e3.x * 64 + lane]);
        acc = fmaf(__int_as_float(e0.y), x0, acc);
        acc = fmaf(__int_as_float(e1.y), x1, acc);
        acc = fmaf(__int_as_float(e2.y), x2, acc);
        acc = fmaf(__int_as_float(e3.y), x3, acc);
    }
    for (; j < n; j++) {
        int2 e = edges[s + j];
        acc = fmaf(__int_as_float(e.y), bf2f(cur[(size_t)e.x * 64 + lane]), acc);
    }
    *dst += acc;
}

// ---------------------------------------------------------------------------
// vsel += bf16 src at selected rows (after layer 1)
// ---------------------------------------------------------------------------
__global__ void k_gather_add(const int* __restrict__ users,
                             const int* __restrict__ items,
                             const unsigned short* __restrict__ src,
                             float* __restrict__ vsel) {
    int t = blockIdx.x * blockDim.x + threadIdx.x;
    int b = t >> 6, d = t & 63;
    vsel[b * 128 + d]      += bf2f(src[(size_t)users[b] * 64 + d]);
    vsel[b * 128 + 64 + d] += bf2f(src[(size_t)(NUM_USERS + items[b]) * 64 + d]);
}

// ---------------------------------------------------------------------------
// MLP head v2: one THREAD per batch row, no cross-lane ops.
// h0[64]/h1[32] live in VGPRs -> 64-wide independent FMA chains (ILP), LDS
// weight reads are wave-uniform broadcasts (conflict-free, b128-vectorized).
// Grid: 64 blocks x 256 threads == BATCH.
// ---------------------------------------------------------------------------
__global__ __launch_bounds__(256) void k_mlp(const float* __restrict__ vsel,
                                             const float* __restrict__ W0,
                                             const float* __restrict__ b0,
                                             const float* __restrict__ W1,
                                             const float* __restrict__ b1,
                                             const float* __restrict__ Wa,
                                             const float* __restrict__ ba,
                                             float* __restrict__ out) {
    __shared__ float sW0[128 * 64];
    __shared__ float sW1[64 * 32];
    __shared__ float sWa[32];
    __shared__ float sb0[64];
    __shared__ float sb1[32];

    for (int i = threadIdx.x; i < 128 * 64; i += 256) sW0[i] = W0[i];
    for (int i = threadIdx.x; i < 64 * 32;  i += 256) sW1[i] = W1[i];
    if (threadIdx.x < 32) sWa[threadIdx.x] = Wa[threadIdx.x];
    if (threadIdx.x < 64) sb0[threadIdx.x] = b0[threadIdx.x];
    if (threadIdx.x >= 64 && threadIdx.x < 96) sb1[threadIdx.x - 64] = b1[threadIdx.x - 64];
    float sba = ba[0];
    __syncthreads();

    int b = blockIdx.x * 256 + threadIdx.x;          // one row per thread
    const float4* v4 = (const float4*)(vsel + (size_t)b * 128);

    float h0[64];
    #pragma unroll
    for (int j = 0; j < 64; j++) h0[j] = sb0[j];

    for (int k0 = 0; k0 < 32; k0++) {                // 32 float4 = 128 inputs
        float4 va = v4[k0];
        float a0 = va.x * 0.25f, a1 = va.y * 0.25f;
        float a2 = va.z * 0.25f, a3 = va.w * 0.25f;
        const float* w = &sW0[(k0 * 4) * 64];
        #pragma unroll
        for (int j = 0; j < 64; j++) {
            h0[j] = fmaf(a0, w[j],       h0[j]);
            h0[j] = fmaf(a1, w[64 + j],  h0[j]);
            h0[j] = fmaf(a2, w[128 + j], h0[j]);
            h0[j] = fmaf(a3, w[192 + j], h0[j]);
        }
    }
    #pragma unroll
    for (int j = 0; j < 64; j++) h0[j] = fmaxf(h0[j], 0.f);

    float h1[32];
    #pragma unroll
    for (int j = 0; j < 32; j++) h1[j] = sb1[j];
    for (int k = 0; k < 64; k++) {
        float a = h0[k];
        const float* w = &sW1[k * 32];
        #pragma unroll
        for (int j = 0; j < 32; j++)
            h1[j] = fmaf(a, w[j], h1[j]);
    }

    float logit = sba;
    #pragma unroll
    for (int j = 0; j < 32; j++)
        logit = fmaf(fmaxf(h1[j], 0.f), sWa[j], logit);

    out[b] = 1.0f / (1.0f + expf(-logit));
}

// ---------------------------------------------------------------------------
extern "C" void kernel_launch(void* const* d_in, const int* in_sizes, int n_in,
                              void* d_out, int out_size, void* d_ws, size_t ws_size,
                              hipStream_t stream) {
    const int*   users = (const int*)  d_in[0];
    const int*   items = (const int*)  d_in[1];
    const int*   rows  = (const int*)  d_in[2];
    const int*   cols  = (const int*)  d_in[3];
    const float* vals  = (const float*)d_in[4];
    const float* ue    = (const float*)d_in[5];
    const float* ie    = (const float*)d_in[6];
    const float* W0    = (const float*)d_in[7];
    const float* b0    = (const float*)d_in[8];
    const float* W1    = (const float*)d_in[9];
    const float* b1    = (const float*)d_in[10];
    const float* Wa    = (const float*)d_in[11];
    const float* ba    = (const float*)d_in[12];
    float* out = (float*)d_out;

    const size_t nodeElems = (size_t)N_NODES * LATENT;   // 9.6 M
    char* ws = (char*)d_ws;
    unsigned short* tabA = (unsigned short*)ws;  ws += nodeElems * 2;            // 19.2 MB
    unsigned short* tabB = (unsigned short*)ws;  ws += nodeElems * 2;            // 19.2 MB
    float* vsel = (float*)ws;                    ws += (size_t)BATCH * 128 * 4;  // 8.39 MB
    int2*  edges  = (int2*)ws;                   ws += (size_t)N_EDGES * 8;      // 19.2 MB
    int2*  staged = (int2*)ws;                   ws += (size_t)N_EDGES * 8;      // 19.2 MB
    int* counts   = (int*)ws;                    ws += N_NODES * 4;
    int* startArr = (int*)ws;                    ws += N_NODES * 4;
    int* cmat     = (int*)ws;                    ws += (size_t)NBKT * NBLK * 4;  // 686 KB
    int* btotal   = (int*)ws;                    ws += NBKT * 4;
    int* bbase    = (int*)ws;                    ws += (NBKT + 1) * 4;

    const int gGrid = (BATCH * 64) / 256;

    // bf16 table + fp32 layer-0 selection
    k_concat_bf16<<<(N_NODES * (LATENT / 4) + 255) / 256, 256, 0, stream>>>(
        (const float4*)ue, (const float4*)ie, (ushort4*)tabA);
    k_sel_init<<<gGrid, 256, 0, stream>>>(users, items, ue, ie, vsel);

    // ---- CSR build: zero global atomics, no row histogram ----
    k_p1a<<<NBLK, 256, 0, stream>>>(rows, cmat);
    k_p1b<<<NBKT, 1024, 0, stream>>>(cmat, btotal);
    k_bscan<<<1, 512, 0, stream>>>(btotal, bbase);
    k_p1c<<<NBLK, 256, 0, stream>>>(rows, cols, vals, cmat, bbase, staged);
    k_p2<<<NBKT, 256, 0, stream>>>(bbase, staged, edges, counts, startArr);

    // layer 1: A -> B (writes every row; no memset needed)
    k_spmm_csr<<<(N_NODES + 3) / 4, 256, 0, stream>>>(startArr, counts, edges, tabA, tabB);
    k_gather_add<<<gGrid, 256, 0, stream>>>(users, items, tabB, vsel);

    // layer 2: B -> A
    k_spmm_csr<<<(N_NODES + 3) / 4, 256, 0, stream>>>(startArr, counts, edges, tabB, tabA);

    // layer 3 (selected rows only) fused with layer-2 gather_add
    k_spmm_sel<<<(2 * BATCH) / 4, 256, 0, stream>>>(users, items, startArr,
                                                    counts, edges, tabA, vsel);

    // MLP head: one thread per row
    k_mlp<<<BATCH / 256, 256, 0, stream>>>(vsel, W0, b0, W1, b1, Wa, ba, out);
}